// Round 1
// 524.699 us; speedup vs baseline: 1.2915x; 1.2915x over previous
//
#include <hip/hip_runtime.h>

// GCNEncoder — round 11: eliminate k_fill's 16x write amplification.
// Old counting-sort (k_count/k_disalloc/k_fill) wrote 105 MB HBM for a 6.4 MB
// elist (each scattered 4B store bounced a 64B line across XCD L2s), 125 µs.
// New: bucketed build (dst>>8 => 391 buckets of 256 nodes):
//   k_hist    per-chunk LDS histogram, 1 atomic per (block,bucket)
//   k_scan    1-block prefix sum -> ordered bucket bases
//   k_scatter per-chunk LDS bin + run reservation; contiguous per-chunk
//             clusters written by one XCD => ~1x amplification (~13 MB)
//   k_fine    one block per bucket: LDS node counts (replaces k_count, zero
//             per-edge global atomics), LDS scan -> ordered rowptr/cnt/dis,
//             CSR fill inside a 16 KB L2-resident region
// Everything downstream (gemm/gather/bn) unchanged. ebuf overlays agg1.

#define SHIFT 8
#define BSZ   256          // nodes per bucket = 1<<SHIFT
#define CHUNK 4096         // edges per block in hist/scatter
#define EPT   (CHUNK/256)  // edges per thread = 16
#define NBMAX 1024         // supports N <= 262144

__device__ __forceinline__ unsigned short f2bf(float f) {
    unsigned int u = __float_as_uint(f);
    unsigned int r = (u + 0x7FFFu + ((u >> 16) & 1u)) >> 16;   // RNE
    return (unsigned short)r;
}
__device__ __forceinline__ float bf2f(unsigned short h) {
    return __uint_as_float(((unsigned int)h) << 16);
}
__device__ __forceinline__ unsigned int pack2bf(float a, float b) {
    return (unsigned int)f2bf(a) | ((unsigned int)f2bf(b) << 16);
}
__device__ __forceinline__ void fma4(float4& acc, float s, const float4& w) {
    acc.x += s * w.x; acc.y += s * w.y; acc.z += s * w.z; acc.w += s * w.w;
}

// ---------- dtype probe: edge_index may be int64 or int32 ----------
__global__ void k_detect(const int* __restrict__ ei32, int* __restrict__ flag) {
    if (threadIdx.x == 0 && blockIdx.x == 0) {
        int o = 0;
        for (int q = 0; q < 16; ++q) o |= ei32[2 * q + 1];
        flag[0] = (o == 0) ? 1 : 0;  // 1 => int64 (high dwords all zero)
    }
}

// ---------- pass 1: bucket histogram (LDS-staged) ----------
__global__ __launch_bounds__(256) void k_hist(const void* __restrict__ eiv,
                                              const int* __restrict__ flag,
                                              int* __restrict__ gcnt,
                                              int E, int N, int NB) {
    __shared__ int h[NBMAX];
    int t = threadIdx.x;
    for (int u = t; u < NB; u += 256) h[u] = 0;
    __syncthreads();
    int base = blockIdx.x * CHUNK;
    int f = flag[0];
    const long long* e64 = (const long long*)eiv;
    const int*       e32 = (const int*)eiv;
#pragma unroll
    for (int r = 0; r < EPT; ++r) {
        int e = base + r * 256 + t;
        if (e < E) {
            int s, d;
            if (f) { s = (int)e64[e]; d = (int)e64[E + e]; }
            else   { s = e32[e];      d = e32[E + e]; }
            if ((unsigned)s < (unsigned)N && (unsigned)d < (unsigned)N)
                atomicAdd(&h[d >> SHIFT], 1);
        }
    }
    __syncthreads();
    for (int u = t; u < NB; u += 256) {
        int c = h[u];
        if (c) atomicAdd(&gcnt[u], c);
    }
}

// ---------- pass 2: exclusive prefix over bucket totals ----------
__global__ void k_scan(const int* __restrict__ gcnt, int* __restrict__ gbase,
                       int* __restrict__ gcur, int NB) {
    __shared__ int sh[1024];
    int t = threadIdx.x;
    int v = (t < NB) ? gcnt[t] : 0;
    sh[t] = v;
    __syncthreads();
    for (int off = 1; off < 1024; off <<= 1) {
        int x = sh[t];
        int y = (t >= off) ? sh[t - off] : 0;
        __syncthreads();
        sh[t] = x + y;
        __syncthreads();
    }
    if (t < NB) {
        int ex = sh[t] - v;
        gbase[t] = ex;
        gcur[t]  = ex;
    }
    if (t == 0) gbase[NB] = sh[1023];
}

// ---------- pass 3: scatter edges into bucket regions, clustered ----------
__global__ __launch_bounds__(256) void k_scatter(const void* __restrict__ eiv,
                                                 const int* __restrict__ flag,
                                                 int* __restrict__ gcur,
                                                 unsigned int* __restrict__ ebuf,
                                                 int E, int N, int NB) {
    __shared__ int lcnt[NBMAX];
    __shared__ int lbase[NBMAX];
    int t = threadIdx.x;
    for (int u = t; u < NB; u += 256) lcnt[u] = 0;
    __syncthreads();
    int base = blockIdx.x * CHUNK;
    int f = flag[0];
    const long long* e64 = (const long long*)eiv;
    const int*       e32 = (const int*)eiv;
    unsigned int ent[EPT];
    int bk[EPT];
    int off[EPT];
#pragma unroll
    for (int r = 0; r < EPT; ++r) {
        int e = base + r * 256 + t;
        bk[r] = -1;
        if (e < E) {
            int s, d;
            if (f) { s = (int)e64[e]; d = (int)e64[E + e]; }
            else   { s = e32[e];      d = e32[E + e]; }
            if ((unsigned)s < (unsigned)N && (unsigned)d < (unsigned)N) {
                int b = d >> SHIFT;
                bk[r]  = b;
                off[r] = atomicAdd(&lcnt[b], 1);
                ent[r] = ((unsigned int)(d & (BSZ - 1)) << 24) | (unsigned int)s;
            }
        }
    }
    __syncthreads();
    for (int u = t; u < NB; u += 256) {
        int c = lcnt[u];
        lbase[u] = c ? atomicAdd(&gcur[u], c) : 0;
    }
    __syncthreads();
#pragma unroll
    for (int r = 0; r < EPT; ++r)
        if (bk[r] >= 0) ebuf[(size_t)lbase[bk[r]] + off[r]] = ent[r];
}

// ---------- pass 4: per-bucket CSR finalize (counts, dis, rowptr, elist) ----
__global__ __launch_bounds__(256) void k_fine(const unsigned int* __restrict__ ebuf,
                                              const int* __restrict__ gbase,
                                              int* __restrict__ cnt,
                                              float* __restrict__ dis,
                                              int* __restrict__ rowptr,
                                              int* __restrict__ elist, int N) {
    __shared__ int lc[BSZ];
    __shared__ int ls[BSZ];
    int t = threadIdx.x;
    int b = blockIdx.x;
    int start = gbase[b], end = gbase[b + 1];
    int m = end - start;
    lc[t] = 0;
    __syncthreads();
    for (int j = t; j < m; j += 256)
        atomicAdd(&lc[ebuf[start + j] >> 24], 1);
    __syncthreads();
    int v = lc[t];
    ls[t] = v;
    __syncthreads();
    for (int off = 1; off < BSZ; off <<= 1) {
        int x = ls[t];
        int y = (t >= off) ? ls[t - off] : 0;
        __syncthreads();
        ls[t] = x + y;
        __syncthreads();
    }
    int ex = ls[t] - v;
    int i = (b << SHIFT) + t;
    if (i < N) {
        cnt[i]    = v;
        dis[i]    = rsqrtf((float)v + 1.0f);
        rowptr[i] = start + ex;
    }
    lc[t] = ex;        // per-node cursor (bucket-relative)
    __syncthreads();
    for (int j = t; j < m; j += 256) {
        unsigned int e = ebuf[start + j];
        int p = atomicAdd(&lc[e >> 24], 1);
        elist[start + p] = (int)(e & 0xFFFFFFu);
    }
}

// ---------- weight transpose: dst[k][o] = src[o][k], K=128 ----------
__global__ __launch_bounds__(256) void k_transpose(const float* __restrict__ src,
                                                   float* __restrict__ dst, int O) {
    int idx = blockIdx.x * 256 + threadIdx.x;
    if (idx >= O * 128) return;
    int k = idx & 127, o = idx >> 7;
    dst[k * O + o] = src[o * 128 + k];
}

// ---------- GEMM1: h1s[n][o] (bf16) = dis[n] * (x[n]·W1[o]) ----------
__global__ __launch_bounds__(256) void k_gemm1(const float* __restrict__ x,
                                               const float* __restrict__ WT1,
                                               const float* __restrict__ dis,
                                               uint2* __restrict__ h1b, int N) {
    int t = threadIdx.x;
    int q = t & 31, g = t >> 5;
    int n0 = blockIdx.x * 32 + g * 4;
    int m0 = min(n0 + 0, N - 1), m1 = min(n0 + 1, N - 1);
    int m2 = min(n0 + 2, N - 1), m3 = min(n0 + 3, N - 1);
    const float4* xr0 = (const float4*)x + (size_t)m0 * 32;
    const float4* xr1 = (const float4*)x + (size_t)m1 * 32;
    const float4* xr2 = (const float4*)x + (size_t)m2 * 32;
    const float4* xr3 = (const float4*)x + (size_t)m3 * 32;
    const float4* wt = (const float4*)WT1;   // row k: 32 float4
    float4 acc0 = make_float4(0.f, 0.f, 0.f, 0.f), acc1 = acc0, acc2 = acc0, acc3 = acc0;
    for (int kq = 0; kq < 32; ++kq) {
        float4 a0 = xr0[kq], a1 = xr1[kq], a2 = xr2[kq], a3 = xr3[kq];
        float4 w0 = wt[(4 * kq + 0) * 32 + q];   // coalesced across q-lanes
        float4 w1 = wt[(4 * kq + 1) * 32 + q];
        float4 w2 = wt[(4 * kq + 2) * 32 + q];
        float4 w3 = wt[(4 * kq + 3) * 32 + q];
        fma4(acc0, a0.x, w0); fma4(acc0, a0.y, w1); fma4(acc0, a0.z, w2); fma4(acc0, a0.w, w3);
        fma4(acc1, a1.x, w0); fma4(acc1, a1.y, w1); fma4(acc1, a1.z, w2); fma4(acc1, a1.w, w3);
        fma4(acc2, a2.x, w0); fma4(acc2, a2.y, w1); fma4(acc2, a2.z, w2); fma4(acc2, a2.w, w3);
        fma4(acc3, a3.x, w0); fma4(acc3, a3.y, w1); fma4(acc3, a3.z, w2); fma4(acc3, a3.w, w3);
    }
    float d0 = dis[m0], d1 = dis[m1], d2 = dis[m2], d3 = dis[m3];
    if (n0 + 0 < N) h1b[(size_t)(n0 + 0) * 32 + q] = make_uint2(pack2bf(d0 * acc0.x, d0 * acc0.y), pack2bf(d0 * acc0.z, d0 * acc0.w));
    if (n0 + 1 < N) h1b[(size_t)(n0 + 1) * 32 + q] = make_uint2(pack2bf(d1 * acc1.x, d1 * acc1.y), pack2bf(d1 * acc1.z, d1 * acc1.w));
    if (n0 + 2 < N) h1b[(size_t)(n0 + 2) * 32 + q] = make_uint2(pack2bf(d2 * acc2.x, d2 * acc2.y), pack2bf(d2 * acc2.z, d2 * acc2.w));
    if (n0 + 3 < N) h1b[(size_t)(n0 + 3) * 32 + q] = make_uint2(pack2bf(d3 * acc3.x, d3 * acc3.y), pack2bf(d3 * acc3.z, d3 * acc3.w));
}

// ---------- layer-1 gather: pre-scaled bf16 rows, 8-way prefetch ----------
// agg1[i] = dis_i * ( sum_edges h1s[s] + h1s[i] )
__global__ __launch_bounds__(256) void k_agg1(const unsigned int* __restrict__ h1b,
                                              const float* __restrict__ dis,
                                              const int* __restrict__ rowptr,
                                              const int* __restrict__ cnt,
                                              const int* __restrict__ elist,
                                              float* __restrict__ agg1, int N) {
    int lane = threadIdx.x & 63;
    int i = blockIdx.x * 4 + (threadIdx.x >> 6);
    if (i >= N) return;
    float accx = 0.f, accy = 0.f;
    int base = rowptr[i], c = cnt[i];
    int j = 0;
    for (; j + 8 <= c; j += 8) {
        int ss[8];
#pragma unroll
        for (int r = 0; r < 8; ++r) ss[r] = elist[base + j + r];   // independent
        unsigned int vv[8];
#pragma unroll
        for (int r = 0; r < 8; ++r) vv[r] = h1b[(size_t)ss[r] * 64 + lane];  // 256B/row
#pragma unroll
        for (int r = 0; r < 8; ++r) {
            accx += bf2f((unsigned short)(vv[r] & 0xFFFF));
            accy += bf2f((unsigned short)(vv[r] >> 16));
        }
    }
    for (; j < c; ++j) {
        int s = elist[base + j];
        unsigned int v = h1b[(size_t)s * 64 + lane];
        accx += bf2f((unsigned short)(v & 0xFFFF));
        accy += bf2f((unsigned short)(v >> 16));
    }
    float di = dis[i];
    unsigned int sv = h1b[(size_t)i * 64 + lane];
    float2 r;
    r.x = di * (accx + bf2f((unsigned short)(sv & 0xFFFF)));
    r.y = di * (accy + bf2f((unsigned short)(sv >> 16)));
    ((float2*)agg1)[(size_t)i * 64 + lane] = r;
}

// ---------- BN stats (proven, fp32 agg1) ----------
__global__ __launch_bounds__(256) void k_bnstats(const float* __restrict__ agg1,
                                                 float* __restrict__ stats, int N) {
    int t = threadIdx.x;
    int f = t & 127, half = t >> 7;
    float s = 0.f, sq = 0.f;
    int stride = gridDim.x * 2;
    for (int r = blockIdx.x * 2 + half; r < N; r += stride) {
        float v = agg1[r * 128 + f];
        s += v; sq += v * v;
    }
    __shared__ float ls[256], lq[256];
    ls[t] = s; lq[t] = sq;
    __syncthreads();
    if (t < 128) {
        atomicAdd(&stats[f], ls[t] + ls[t + 128]);
        atomicAdd(&stats[128 + f], lq[t] + lq[t + 128]);
    }
}

// ---------- BN finalize (proven) ----------
__global__ void k_bnfin(float* __restrict__ stats, const float* __restrict__ gamma,
                        const float* __restrict__ beta, int N) {
    int f = threadIdx.x;
    if (f >= 128) return;
    float invN = 1.0f / (float)N;
    float mean = stats[f] * invN;
    float var = stats[128 + f] * invN - mean * mean;
    var = fmaxf(var, 0.f);
    float inv = rsqrtf(var + 1e-5f);
    float sc = gamma[f] * inv;
    stats[256 + f] = sc;
    stats[384 + f] = beta[f] - mean * sc;
}

// ---------- GEMM2: h2s[n][o] (bf16) = dis[n] * (relu(bn(agg1[n]))·W2[o]) ----------
__global__ __launch_bounds__(256) void k_gemm2(const float* __restrict__ agg1,
                                               const float* __restrict__ WT2,
                                               const float* __restrict__ stats,
                                               const float* __restrict__ dis,
                                               uint2* __restrict__ h2b, int N) {
    int t = threadIdx.x;
    int q = t & 15, g = t >> 4;
    int n0 = blockIdx.x * 64 + g * 4;
    int m0 = min(n0 + 0, N - 1), m1 = min(n0 + 1, N - 1);
    int m2 = min(n0 + 2, N - 1), m3 = min(n0 + 3, N - 1);
    const float4* ar0 = (const float4*)agg1 + (size_t)m0 * 32;
    const float4* ar1 = (const float4*)agg1 + (size_t)m1 * 32;
    const float4* ar2 = (const float4*)agg1 + (size_t)m2 * 32;
    const float4* ar3 = (const float4*)agg1 + (size_t)m3 * 32;
    const float4* wt = (const float4*)WT2;   // row k: 16 float4
    const float4* st = (const float4*)stats;
    float4 acc0 = make_float4(0.f, 0.f, 0.f, 0.f), acc1 = acc0, acc2 = acc0, acc3 = acc0;
    for (int kq = 0; kq < 32; ++kq) {
        float4 sc = st[64 + kq], sh = st[96 + kq];
        float4 a0 = ar0[kq], a1 = ar1[kq], a2 = ar2[kq], a3 = ar3[kq];
        float4 r0, r1, r2, r3;
        r0.x = fmaxf(a0.x * sc.x + sh.x, 0.f); r0.y = fmaxf(a0.y * sc.y + sh.y, 0.f);
        r0.z = fmaxf(a0.z * sc.z + sh.z, 0.f); r0.w = fmaxf(a0.w * sc.w + sh.w, 0.f);
        r1.x = fmaxf(a1.x * sc.x + sh.x, 0.f); r1.y = fmaxf(a1.y * sc.y + sh.y, 0.f);
        r1.z = fmaxf(a1.z * sc.z + sh.z, 0.f); r1.w = fmaxf(a1.w * sc.w + sh.w, 0.f);
        r2.x = fmaxf(a2.x * sc.x + sh.x, 0.f); r2.y = fmaxf(a2.y * sc.y + sh.y, 0.f);
        r2.z = fmaxf(a2.z * sc.z + sh.z, 0.f); r2.w = fmaxf(a2.w * sc.w + sh.w, 0.f);
        r3.x = fmaxf(a3.x * sc.x + sh.x, 0.f); r3.y = fmaxf(a3.y * sc.y + sh.y, 0.f);
        r3.z = fmaxf(a3.z * sc.z + sh.z, 0.f); r3.w = fmaxf(a3.w * sc.w + sh.w, 0.f);
        float4 w0 = wt[(4 * kq + 0) * 16 + q];   // coalesced across q-lanes
        float4 w1 = wt[(4 * kq + 1) * 16 + q];
        float4 w2 = wt[(4 * kq + 2) * 16 + q];
        float4 w3 = wt[(4 * kq + 3) * 16 + q];
        fma4(acc0, r0.x, w0); fma4(acc0, r0.y, w1); fma4(acc0, r0.z, w2); fma4(acc0, r0.w, w3);
        fma4(acc1, r1.x, w0); fma4(acc1, r1.y, w1); fma4(acc1, r1.z, w2); fma4(acc1, r1.w, w3);
        fma4(acc2, r2.x, w0); fma4(acc2, r2.y, w1); fma4(acc2, r2.z, w2); fma4(acc2, r2.w, w3);
        fma4(acc3, r3.x, w0); fma4(acc3, r3.y, w1); fma4(acc3, r3.z, w2); fma4(acc3, r3.w, w3);
    }
    float d0 = dis[m0], d1 = dis[m1], d2 = dis[m2], d3 = dis[m3];
    if (n0 + 0 < N) h2b[(size_t)(n0 + 0) * 16 + q] = make_uint2(pack2bf(d0 * acc0.x, d0 * acc0.y), pack2bf(d0 * acc0.z, d0 * acc0.w));
    if (n0 + 1 < N) h2b[(size_t)(n0 + 1) * 16 + q] = make_uint2(pack2bf(d1 * acc1.x, d1 * acc1.y), pack2bf(d1 * acc1.z, d1 * acc1.w));
    if (n0 + 2 < N) h2b[(size_t)(n0 + 2) * 16 + q] = make_uint2(pack2bf(d2 * acc2.x, d2 * acc2.y), pack2bf(d2 * acc2.z, d2 * acc2.w));
    if (n0 + 3 < N) h2b[(size_t)(n0 + 3) * 16 + q] = make_uint2(pack2bf(d3 * acc3.x, d3 * acc3.y), pack2bf(d3 * acc3.z, d3 * acc3.w));
}

// ---------- layer-2 gather: pre-scaled bf16 rows, 8-way prefetch ----------
// out[i] = dis_i * ( sum_edges h2s[s] + h2s[i] ) + b2
__global__ __launch_bounds__(256) void k_agg2(const unsigned short* __restrict__ h2b,
                                              const float* __restrict__ dis,
                                              const int* __restrict__ rowptr,
                                              const int* __restrict__ cnt,
                                              const int* __restrict__ elist,
                                              const float* __restrict__ b2,
                                              float* __restrict__ out, int N) {
    int lane = threadIdx.x & 63;
    int i = blockIdx.x * 4 + (threadIdx.x >> 6);
    if (i >= N) return;
    float acc = 0.f;
    int base = rowptr[i], c = cnt[i];
    int j = 0;
    for (; j + 8 <= c; j += 8) {
        int ss[8];
#pragma unroll
        for (int r = 0; r < 8; ++r) ss[r] = elist[base + j + r];   // independent
        unsigned short vv[8];
#pragma unroll
        for (int r = 0; r < 8; ++r) vv[r] = h2b[(size_t)ss[r] * 64 + lane];  // 128B/row
#pragma unroll
        for (int r = 0; r < 8; ++r) acc += bf2f(vv[r]);
    }
    for (; j < c; ++j) {
        int s = elist[base + j];
        acc += bf2f(h2b[(size_t)s * 64 + lane]);
    }
    float di = dis[i];
    float self = bf2f(h2b[(size_t)i * 64 + lane]);
    out[(size_t)i * 64 + lane] = di * (acc + self) + b2[lane];
}

extern "C" void kernel_launch(void* const* d_in, const int* in_sizes, int n_in,
                              void* d_out, int out_size, void* d_ws, size_t ws_size,
                              hipStream_t stream) {
    const float* x     = (const float*)d_in[0];
    const void*  ei    = d_in[1];            // int64 or int32, probed on device
    const float* W1    = (const float*)d_in[2];
    // d_in[3] = b1: cancels exactly through BatchNorm -> skipped
    const float* gamma = (const float*)d_in[4];
    const float* beta  = (const float*)d_in[5];
    const float* W2    = (const float*)d_in[6];
    const float* b2    = (const float*)d_in[7];
    float* out = (float*)d_out;

    int N = in_sizes[0] / 128;
    int E = in_sizes[1] / 2;
    size_t NF = (size_t)N * 128;
    int NB = (N + BSZ - 1) >> SHIFT;         // 391 buckets for N=100000 (<= NBMAX)

    // ---- workspace layout (~85 MB; all regions 16B-aligned) ----
    size_t Na = ((size_t)N + 3) & ~(size_t)3;
    size_t Ea = ((size_t)E + 3) & ~(size_t)3;
    int*   cnt    = (int*)d_ws;                          // Na
    int*   rowptr = cnt + Na;                            // Na
    int*   gcnt   = rowptr + Na;                         // 1024
    int*   gbase  = gcnt + 1024;                         // 1028 (NB+1 used)
    int*   gcur   = gbase + 1028;                        // 1024
    int*   flagA  = gcur + 1024;                         // 4
    float* stats  = (float*)(flagA + 4);                 // 512
    float* dis    = stats + 512;                         // Na
    int*   elist  = (int*)(dis + Na);                    // Ea
    unsigned int* h1b = (unsigned int*)(elist + Ea);     // Na*64 uints (bf16x2)
    float* agg1   = (float*)(h1b + Na * 64);             // Na*128 f32
    unsigned int* ebuf = (unsigned int*)agg1;            // overlay: dead before k_agg1
    float* WT1    = agg1 + Na * 128;                     // 128*128
    float* WT2    = WT1 + 128 * 128;                     // 128*64
    unsigned int* h2b = h1b;                             // overlay: h1 dead after agg1

    hipMemsetAsync(gcnt, 0, 1024 * sizeof(int), stream);
    hipMemsetAsync(stats, 0, 512 * sizeof(float), stream);

    k_detect<<<1, 64, 0, stream>>>((const int*)ei, flagA);

    int gC   = (E + CHUNK - 1) / CHUNK;      // 391 chunks
    int gG1  = (N + 31) / 32;
    int gG2  = (N + 63) / 64;
    int gAgg = (N + 3) / 4;

    k_transpose<<<64, 256, 0, stream>>>(W1, WT1, 128);   // 16384 elems
    k_transpose<<<32, 256, 0, stream>>>(W2, WT2, 64);    // 8192 elems
    k_hist<<<gC, 256, 0, stream>>>(ei, flagA, gcnt, E, N, NB);
    k_scan<<<1, 1024, 0, stream>>>(gcnt, gbase, gcur, NB);
    k_scatter<<<gC, 256, 0, stream>>>(ei, flagA, gcur, ebuf, E, N, NB);
    k_fine<<<NB, 256, 0, stream>>>(ebuf, gbase, cnt, dis, rowptr, elist, N);
    k_gemm1<<<gG1, 256, 0, stream>>>(x, WT1, dis, (uint2*)h1b, N);
    k_agg1<<<gAgg, 256, 0, stream>>>(h1b, dis, rowptr, cnt, elist, agg1, N);
    k_bnstats<<<500, 256, 0, stream>>>(agg1, stats, N);
    k_bnfin<<<1, 128, 0, stream>>>(stats, gamma, beta, N);
    k_gemm2<<<gG2, 256, 0, stream>>>(agg1, WT2, stats, dis, (uint2*)h2b, N);
    k_agg2<<<gAgg, 256, 0, stream>>>((const unsigned short*)h2b, dis, rowptr, cnt, elist, b2, out, N);
}

// Round 2
// 459.284 us; speedup vs baseline: 1.4755x; 1.1424x over previous
//
#include <hip/hip_runtime.h>

// GCNEncoder — round 12: MFMA-ize GEMM1.
// R11 fixed the CSR build (677->525). k_gemm1 (120us, VALUBusy 30%, MfmaUtil 0)
// was a latency-bound scalar-FMA loop. Now: mfma_f32_16x16x32_bf16 with exact
// bf16 hi/lo split (x = hi + lo; h = hi*Whi + hi*Wlo + lo*Whi; dropped lo*lo
// term is ~2^-16 relative) -> fp32-grade accuracy, matrix-core throughput.
// A (x) fragments built in LDS per 64-row block; W fragments pre-converted
// once (k_prepw) into frag-ordered L2-resident buffers. A/B packed with the
// SAME k-map (k = 8*(lane>>4)+j) so any HW k-permutation cancels (bijection).
// C/D layout per m89: col = lane&15, row = (lane>>4)*4 + reg.

#define SHIFT 8
#define BSZ   256          // nodes per bucket = 1<<SHIFT
#define CHUNK 4096         // edges per block in hist/scatter
#define EPT   (CHUNK/256)  // edges per thread = 16
#define NBMAX 1024         // supports N <= 262144

typedef short bf16x8 __attribute__((ext_vector_type(8)));
typedef float f32x4  __attribute__((ext_vector_type(4)));

__device__ __forceinline__ unsigned short f2bf(float f) {
    unsigned int u = __float_as_uint(f);
    unsigned int r = (u + 0x7FFFu + ((u >> 16) & 1u)) >> 16;   // RNE
    return (unsigned short)r;
}
__device__ __forceinline__ float bf2f(unsigned short h) {
    return __uint_as_float(((unsigned int)h) << 16);
}
__device__ __forceinline__ unsigned int pack2bf(float a, float b) {
    return (unsigned int)f2bf(a) | ((unsigned int)f2bf(b) << 16);
}
__device__ __forceinline__ void fma4(float4& acc, float s, const float4& w) {
    acc.x += s * w.x; acc.y += s * w.y; acc.z += s * w.z; acc.w += s * w.w;
}

// exact hi/lo split of a float pair, packed as bf16x2 (truncation split:
// x == bf2f(hi) + lo exactly; lo then truncated to bf16, residual ~2^-17|x|)
__device__ __forceinline__ void split2(float a, float b, unsigned int& hi, unsigned int& lo) {
    unsigned int ua = __float_as_uint(a), ub = __float_as_uint(b);
    unsigned int ha = ua & 0xFFFF0000u,  hb = ub & 0xFFFF0000u;
    hi = (ha >> 16) | hb;
    float la = a - __uint_as_float(ha);
    float lb = b - __uint_as_float(hb);
    lo = (__float_as_uint(la) >> 16) | (__float_as_uint(lb) & 0xFFFF0000u);
}

// ---------- dtype probe: edge_index may be int64 or int32 ----------
__global__ void k_detect(const int* __restrict__ ei32, int* __restrict__ flag) {
    if (threadIdx.x == 0 && blockIdx.x == 0) {
        int o = 0;
        for (int q = 0; q < 16; ++q) o |= ei32[2 * q + 1];
        flag[0] = (o == 0) ? 1 : 0;  // 1 => int64 (high dwords all zero)
    }
}

// ---------- pass 1: bucket histogram (LDS-staged) ----------
__global__ __launch_bounds__(256) void k_hist(const void* __restrict__ eiv,
                                              const int* __restrict__ flag,
                                              int* __restrict__ gcnt,
                                              int E, int N, int NB) {
    __shared__ int h[NBMAX];
    int t = threadIdx.x;
    for (int u = t; u < NB; u += 256) h[u] = 0;
    __syncthreads();
    int base = blockIdx.x * CHUNK;
    int f = flag[0];
    const long long* e64 = (const long long*)eiv;
    const int*       e32 = (const int*)eiv;
#pragma unroll
    for (int r = 0; r < EPT; ++r) {
        int e = base + r * 256 + t;
        if (e < E) {
            int s, d;
            if (f) { s = (int)e64[e]; d = (int)e64[E + e]; }
            else   { s = e32[e];      d = e32[E + e]; }
            if ((unsigned)s < (unsigned)N && (unsigned)d < (unsigned)N)
                atomicAdd(&h[d >> SHIFT], 1);
        }
    }
    __syncthreads();
    for (int u = t; u < NB; u += 256) {
        int c = h[u];
        if (c) atomicAdd(&gcnt[u], c);
    }
}

// ---------- pass 2: exclusive prefix over bucket totals ----------
__global__ void k_scan(const int* __restrict__ gcnt, int* __restrict__ gbase,
                       int* __restrict__ gcur, int NB) {
    __shared__ int sh[1024];
    int t = threadIdx.x;
    int v = (t < NB) ? gcnt[t] : 0;
    sh[t] = v;
    __syncthreads();
    for (int off = 1; off < 1024; off <<= 1) {
        int x = sh[t];
        int y = (t >= off) ? sh[t - off] : 0;
        __syncthreads();
        sh[t] = x + y;
        __syncthreads();
    }
    if (t < NB) {
        int ex = sh[t] - v;
        gbase[t] = ex;
        gcur[t]  = ex;
    }
    if (t == 0) gbase[NB] = sh[1023];
}

// ---------- pass 3: scatter edges into bucket regions, clustered ----------
__global__ __launch_bounds__(256) void k_scatter(const void* __restrict__ eiv,
                                                 const int* __restrict__ flag,
                                                 int* __restrict__ gcur,
                                                 unsigned int* __restrict__ ebuf,
                                                 int E, int N, int NB) {
    __shared__ int lcnt[NBMAX];
    __shared__ int lbase[NBMAX];
    int t = threadIdx.x;
    for (int u = t; u < NB; u += 256) lcnt[u] = 0;
    __syncthreads();
    int base = blockIdx.x * CHUNK;
    int f = flag[0];
    const long long* e64 = (const long long*)eiv;
    const int*       e32 = (const int*)eiv;
    unsigned int ent[EPT];
    int bk[EPT];
    int off[EPT];
#pragma unroll
    for (int r = 0; r < EPT; ++r) {
        int e = base + r * 256 + t;
        bk[r] = -1;
        if (e < E) {
            int s, d;
            if (f) { s = (int)e64[e]; d = (int)e64[E + e]; }
            else   { s = e32[e];      d = e32[E + e]; }
            if ((unsigned)s < (unsigned)N && (unsigned)d < (unsigned)N) {
                int b = d >> SHIFT;
                bk[r]  = b;
                off[r] = atomicAdd(&lcnt[b], 1);
                ent[r] = ((unsigned int)(d & (BSZ - 1)) << 24) | (unsigned int)s;
            }
        }
    }
    __syncthreads();
    for (int u = t; u < NB; u += 256) {
        int c = lcnt[u];
        lbase[u] = c ? atomicAdd(&gcur[u], c) : 0;
    }
    __syncthreads();
#pragma unroll
    for (int r = 0; r < EPT; ++r)
        if (bk[r] >= 0) ebuf[(size_t)lbase[bk[r]] + off[r]] = ent[r];
}

// ---------- pass 4: per-bucket CSR finalize (counts, dis, rowptr, elist) ----
__global__ __launch_bounds__(256) void k_fine(const unsigned int* __restrict__ ebuf,
                                              const int* __restrict__ gbase,
                                              int* __restrict__ cnt,
                                              float* __restrict__ dis,
                                              int* __restrict__ rowptr,
                                              int* __restrict__ elist, int N) {
    __shared__ int lc[BSZ];
    __shared__ int ls[BSZ];
    int t = threadIdx.x;
    int b = blockIdx.x;
    int start = gbase[b], end = gbase[b + 1];
    int m = end - start;
    lc[t] = 0;
    __syncthreads();
    for (int j = t; j < m; j += 256)
        atomicAdd(&lc[ebuf[start + j] >> 24], 1);
    __syncthreads();
    int v = lc[t];
    ls[t] = v;
    __syncthreads();
    for (int off = 1; off < BSZ; off <<= 1) {
        int x = ls[t];
        int y = (t >= off) ? ls[t - off] : 0;
        __syncthreads();
        ls[t] = x + y;
        __syncthreads();
    }
    int ex = ls[t] - v;
    int i = (b << SHIFT) + t;
    if (i < N) {
        cnt[i]    = v;
        dis[i]    = rsqrtf((float)v + 1.0f);
        rowptr[i] = start + ex;
    }
    lc[t] = ex;        // per-node cursor (bucket-relative)
    __syncthreads();
    for (int j = t; j < m; j += 256) {
        unsigned int e = ebuf[start + j];
        int p = atomicAdd(&lc[e >> 24], 1);
        elist[start + p] = (int)(e & 0xFFFFFFu);
    }
}

// ---------- weight transpose: dst[k][o] = src[o][k], K=128 ----------
__global__ __launch_bounds__(256) void k_transpose(const float* __restrict__ src,
                                                   float* __restrict__ dst, int O) {
    int idx = blockIdx.x * 256 + threadIdx.x;
    if (idx >= O * 128) return;
    int k = idx & 127, o = idx >> 7;
    dst[k * O + o] = src[o * 128 + k];
}

// ---------- W -> fragment-ordered bf16 hi/lo buffers ----------
// slot idx = (nt*4 + kt)*64 + lane ; lane holds B[k][n] for n = nt*16+(lane&15),
// k = kt*32 + 8*(lane>>4) + j, j=0..7 packed low-to-high (same k-map as A).
__global__ __launch_bounds__(256) void k_prepw(const float* __restrict__ W,
                                               uint4* __restrict__ Whi,
                                               uint4* __restrict__ Wlo, int NT) {
    int idx = blockIdx.x * 256 + threadIdx.x;
    if (idx >= NT * 4 * 64) return;
    int lane = idx & 63, kt = (idx >> 6) & 3, nt = idx >> 8;
    int o = nt * 16 + (lane & 15);
    int k0 = kt * 32 + (lane >> 4) * 8;
    const float* p = W + (size_t)o * 128 + k0;
    unsigned int h[4], l[4];
#pragma unroll
    for (int pr = 0; pr < 4; ++pr) split2(p[2 * pr], p[2 * pr + 1], h[pr], l[pr]);
    Whi[idx] = make_uint4(h[0], h[1], h[2], h[3]);
    Wlo[idx] = make_uint4(l[0], l[1], l[2], l[3]);
}

// ---------- GEMM1 (MFMA): h1s[n][o] (bf16) = dis[n] * (x[n]·W1[o]) ----------
// block = 64 rows; phase 1 builds x hi/lo fragments in LDS; wave w computes
// rows [n0+16w, n0+16w+16) x all 128 cols via 8nt x 4kt x 3 MFMAs.
__global__ __launch_bounds__(256) void k_gemm1(const float* __restrict__ x,
                                               const uint4* __restrict__ Whi,
                                               const uint4* __restrict__ Wlo,
                                               const float* __restrict__ dis,
                                               unsigned short* __restrict__ h1b, int N) {
    __shared__ uint4 Ahi[1024];   // [ (c*4+kt)*64 + lane ]
    __shared__ uint4 Alo[1024];
    int t = threadIdx.x;
    int n0 = blockIdx.x * 64;
    // ---- phase 1: x -> hi/lo fragments in LDS ----
    for (int s = t; s < 1024; s += 256) {
        int lane = s & 63, kt = (s >> 6) & 3, c = s >> 8;
        int row = n0 + c * 16 + (lane & 15);
        int rr = min(row, N - 1);
        int k0 = kt * 32 + (lane >> 4) * 8;
        const float4* p = (const float4*)(x + (size_t)rr * 128 + k0);
        float4 u0 = p[0], u1 = p[1];
        unsigned int h0, h1, h2, h3, l0, l1, l2, l3;
        split2(u0.x, u0.y, h0, l0);
        split2(u0.z, u0.w, h1, l1);
        split2(u1.x, u1.y, h2, l2);
        split2(u1.z, u1.w, h3, l3);
        Ahi[s] = make_uint4(h0, h1, h2, h3);
        Alo[s] = make_uint4(l0, l1, l2, l3);
    }
    __syncthreads();
    // ---- phase 2: MFMA ----
    int w = t >> 6, lane = t & 63;
    bf16x8 ah[4], al[4];
#pragma unroll
    for (int kt = 0; kt < 4; ++kt) {
        ah[kt] = ((const bf16x8*)Ahi)[(w * 4 + kt) * 64 + lane];
        al[kt] = ((const bf16x8*)Alo)[(w * 4 + kt) * 64 + lane];
    }
    f32x4 acc[8];
#pragma unroll
    for (int nt = 0; nt < 8; ++nt) {
        acc[nt] = (f32x4)(0.f);
#pragma unroll
        for (int kt = 0; kt < 4; ++kt) {
            bf16x8 bh = ((const bf16x8*)Whi)[(nt * 4 + kt) * 64 + lane];
            bf16x8 bl = ((const bf16x8*)Wlo)[(nt * 4 + kt) * 64 + lane];
            acc[nt] = __builtin_amdgcn_mfma_f32_16x16x32_bf16(ah[kt], bh, acc[nt], 0, 0, 0);
            acc[nt] = __builtin_amdgcn_mfma_f32_16x16x32_bf16(ah[kt], bl, acc[nt], 0, 0, 0);
            acc[nt] = __builtin_amdgcn_mfma_f32_16x16x32_bf16(al[kt], bh, acc[nt], 0, 0, 0);
        }
    }
    // ---- epilogue: scale by dis, pack bf16, store ----
    int r0 = n0 + w * 16 + (lane >> 4) * 4;
    float dv[4];
#pragma unroll
    for (int r = 0; r < 4; ++r) {
        int row = r0 + r;
        dv[r] = (row < N) ? dis[row] : 0.f;
    }
#pragma unroll
    for (int nt = 0; nt < 8; ++nt) {
        int col = nt * 16 + (lane & 15);
#pragma unroll
        for (int r = 0; r < 4; ++r) {
            int row = r0 + r;
            if (row < N) h1b[(size_t)row * 128 + col] = f2bf(dv[r] * acc[nt][r]);
        }
    }
}

// ---------- layer-1 gather: pre-scaled bf16 rows, 8-way prefetch ----------
// agg1[i] = dis_i * ( sum_edges h1s[s] + h1s[i] )
__global__ __launch_bounds__(256) void k_agg1(const unsigned int* __restrict__ h1b,
                                              const float* __restrict__ dis,
                                              const int* __restrict__ rowptr,
                                              const int* __restrict__ cnt,
                                              const int* __restrict__ elist,
                                              float* __restrict__ agg1, int N) {
    int lane = threadIdx.x & 63;
    int i = blockIdx.x * 4 + (threadIdx.x >> 6);
    if (i >= N) return;
    float accx = 0.f, accy = 0.f;
    int base = rowptr[i], c = cnt[i];
    int j = 0;
    for (; j + 8 <= c; j += 8) {
        int ss[8];
#pragma unroll
        for (int r = 0; r < 8; ++r) ss[r] = elist[base + j + r];   // independent
        unsigned int vv[8];
#pragma unroll
        for (int r = 0; r < 8; ++r) vv[r] = h1b[(size_t)ss[r] * 64 + lane];  // 256B/row
#pragma unroll
        for (int r = 0; r < 8; ++r) {
            accx += bf2f((unsigned short)(vv[r] & 0xFFFF));
            accy += bf2f((unsigned short)(vv[r] >> 16));
        }
    }
    for (; j < c; ++j) {
        int s = elist[base + j];
        unsigned int v = h1b[(size_t)s * 64 + lane];
        accx += bf2f((unsigned short)(v & 0xFFFF));
        accy += bf2f((unsigned short)(v >> 16));
    }
    float di = dis[i];
    unsigned int sv = h1b[(size_t)i * 64 + lane];
    float2 r;
    r.x = di * (accx + bf2f((unsigned short)(sv & 0xFFFF)));
    r.y = di * (accy + bf2f((unsigned short)(sv >> 16)));
    ((float2*)agg1)[(size_t)i * 64 + lane] = r;
}

// ---------- BN stats (proven, fp32 agg1) ----------
__global__ __launch_bounds__(256) void k_bnstats(const float* __restrict__ agg1,
                                                 float* __restrict__ stats, int N) {
    int t = threadIdx.x;
    int f = t & 127, half = t >> 7;
    float s = 0.f, sq = 0.f;
    int stride = gridDim.x * 2;
    for (int r = blockIdx.x * 2 + half; r < N; r += stride) {
        float v = agg1[r * 128 + f];
        s += v; sq += v * v;
    }
    __shared__ float ls[256], lq[256];
    ls[t] = s; lq[t] = sq;
    __syncthreads();
    if (t < 128) {
        atomicAdd(&stats[f], ls[t] + ls[t + 128]);
        atomicAdd(&stats[128 + f], lq[t] + lq[t + 128]);
    }
}

// ---------- BN finalize (proven) ----------
__global__ void k_bnfin(float* __restrict__ stats, const float* __restrict__ gamma,
                        const float* __restrict__ beta, int N) {
    int f = threadIdx.x;
    if (f >= 128) return;
    float invN = 1.0f / (float)N;
    float mean = stats[f] * invN;
    float var = stats[128 + f] * invN - mean * mean;
    var = fmaxf(var, 0.f);
    float inv = rsqrtf(var + 1e-5f);
    float sc = gamma[f] * inv;
    stats[256 + f] = sc;
    stats[384 + f] = beta[f] - mean * sc;
}

// ---------- GEMM2: h2s[n][o] (bf16) = dis[n] * (relu(bn(agg1[n]))·W2[o]) ----------
__global__ __launch_bounds__(256) void k_gemm2(const float* __restrict__ agg1,
                                               const float* __restrict__ WT2,
                                               const float* __restrict__ stats,
                                               const float* __restrict__ dis,
                                               uint2* __restrict__ h2b, int N) {
    int t = threadIdx.x;
    int q = t & 15, g = t >> 4;
    int n0 = blockIdx.x * 64 + g * 4;
    int m0 = min(n0 + 0, N - 1), m1 = min(n0 + 1, N - 1);
    int m2 = min(n0 + 2, N - 1), m3 = min(n0 + 3, N - 1);
    const float4* ar0 = (const float4*)agg1 + (size_t)m0 * 32;
    const float4* ar1 = (const float4*)agg1 + (size_t)m1 * 32;
    const float4* ar2 = (const float4*)agg1 + (size_t)m2 * 32;
    const float4* ar3 = (const float4*)agg1 + (size_t)m3 * 32;
    const float4* wt = (const float4*)WT2;   // row k: 16 float4
    const float4* st = (const float4*)stats;
    float4 acc0 = make_float4(0.f, 0.f, 0.f, 0.f), acc1 = acc0, acc2 = acc0, acc3 = acc0;
    for (int kq = 0; kq < 32; ++kq) {
        float4 sc = st[64 + kq], sh = st[96 + kq];
        float4 a0 = ar0[kq], a1 = ar1[kq], a2 = ar2[kq], a3 = ar3[kq];
        float4 r0, r1, r2, r3;
        r0.x = fmaxf(a0.x * sc.x + sh.x, 0.f); r0.y = fmaxf(a0.y * sc.y + sh.y, 0.f);
        r0.z = fmaxf(a0.z * sc.z + sh.z, 0.f); r0.w = fmaxf(a0.w * sc.w + sh.w, 0.f);
        r1.x = fmaxf(a1.x * sc.x + sh.x, 0.f); r1.y = fmaxf(a1.y * sc.y + sh.y, 0.f);
        r1.z = fmaxf(a1.z * sc.z + sh.z, 0.f); r1.w = fmaxf(a1.w * sc.w + sh.w, 0.f);
        r2.x = fmaxf(a2.x * sc.x + sh.x, 0.f); r2.y = fmaxf(a2.y * sc.y + sh.y, 0.f);
        r2.z = fmaxf(a2.z * sc.z + sh.z, 0.f); r2.w = fmaxf(a2.w * sc.w + sh.w, 0.f);
        r3.x = fmaxf(a3.x * sc.x + sh.x, 0.f); r3.y = fmaxf(a3.y * sc.y + sh.y, 0.f);
        r3.z = fmaxf(a3.z * sc.z + sh.z, 0.f); r3.w = fmaxf(a3.w * sc.w + sh.w, 0.f);
        float4 w0 = wt[(4 * kq + 0) * 16 + q];   // coalesced across q-lanes
        float4 w1 = wt[(4 * kq + 1) * 16 + q];
        float4 w2 = wt[(4 * kq + 2) * 16 + q];
        float4 w3 = wt[(4 * kq + 3) * 16 + q];
        fma4(acc0, r0.x, w0); fma4(acc0, r0.y, w1); fma4(acc0, r0.z, w2); fma4(acc0, r0.w, w3);
        fma4(acc1, r1.x, w0); fma4(acc1, r1.y, w1); fma4(acc1, r1.z, w2); fma4(acc1, r1.w, w3);
        fma4(acc2, r2.x, w0); fma4(acc2, r2.y, w1); fma4(acc2, r2.z, w2); fma4(acc2, r2.w, w3);
        fma4(acc3, r3.x, w0); fma4(acc3, r3.y, w1); fma4(acc3, r3.z, w2); fma4(acc3, r3.w, w3);
    }
    float d0 = dis[m0], d1 = dis[m1], d2 = dis[m2], d3 = dis[m3];
    if (n0 + 0 < N) h2b[(size_t)(n0 + 0) * 16 + q] = make_uint2(pack2bf(d0 * acc0.x, d0 * acc0.y), pack2bf(d0 * acc0.z, d0 * acc0.w));
    if (n0 + 1 < N) h2b[(size_t)(n0 + 1) * 16 + q] = make_uint2(pack2bf(d1 * acc1.x, d1 * acc1.y), pack2bf(d1 * acc1.z, d1 * acc1.w));
    if (n0 + 2 < N) h2b[(size_t)(n0 + 2) * 16 + q] = make_uint2(pack2bf(d2 * acc2.x, d2 * acc2.y), pack2bf(d2 * acc2.z, d2 * acc2.w));
    if (n0 + 3 < N) h2b[(size_t)(n0 + 3) * 16 + q] = make_uint2(pack2bf(d3 * acc3.x, d3 * acc3.y), pack2bf(d3 * acc3.z, d3 * acc3.w));
}

// ---------- layer-2 gather: pre-scaled bf16 rows, 8-way prefetch ----------
// out[i] = dis_i * ( sum_edges h2s[s] + h2s[i] ) + b2
__global__ __launch_bounds__(256) void k_agg2(const unsigned short* __restrict__ h2b,
                                              const float* __restrict__ dis,
                                              const int* __restrict__ rowptr,
                                              const int* __restrict__ cnt,
                                              const int* __restrict__ elist,
                                              const float* __restrict__ b2,
                                              float* __restrict__ out, int N) {
    int lane = threadIdx.x & 63;
    int i = blockIdx.x * 4 + (threadIdx.x >> 6);
    if (i >= N) return;
    float acc = 0.f;
    int base = rowptr[i], c = cnt[i];
    int j = 0;
    for (; j + 8 <= c; j += 8) {
        int ss[8];
#pragma unroll
        for (int r = 0; r < 8; ++r) ss[r] = elist[base + j + r];   // independent
        unsigned short vv[8];
#pragma unroll
        for (int r = 0; r < 8; ++r) vv[r] = h2b[(size_t)ss[r] * 64 + lane];  // 128B/row
#pragma unroll
        for (int r = 0; r < 8; ++r) acc += bf2f(vv[r]);
    }
    for (; j < c; ++j) {
        int s = elist[base + j];
        acc += bf2f(h2b[(size_t)s * 64 + lane]);
    }
    float di = dis[i];
    float self = bf2f(h2b[(size_t)i * 64 + lane]);
    out[(size_t)i * 64 + lane] = di * (acc + self) + b2[lane];
}

extern "C" void kernel_launch(void* const* d_in, const int* in_sizes, int n_in,
                              void* d_out, int out_size, void* d_ws, size_t ws_size,
                              hipStream_t stream) {
    const float* x     = (const float*)d_in[0];
    const void*  ei    = d_in[1];            // int64 or int32, probed on device
    const float* W1    = (const float*)d_in[2];
    // d_in[3] = b1: cancels exactly through BatchNorm -> skipped
    const float* gamma = (const float*)d_in[4];
    const float* beta  = (const float*)d_in[5];
    const float* W2    = (const float*)d_in[6];
    const float* b2    = (const float*)d_in[7];
    float* out = (float*)d_out;

    int N = in_sizes[0] / 128;
    int E = in_sizes[1] / 2;
    int NB = (N + BSZ - 1) >> SHIFT;         // 391 buckets for N=100000 (<= NBMAX)

    // ---- workspace layout (~85 MB; all regions 16B-aligned) ----
    size_t Na = ((size_t)N + 3) & ~(size_t)3;
    size_t Ea = ((size_t)E + 3) & ~(size_t)3;
    int*   cnt    = (int*)d_ws;                          // Na
    int*   rowptr = cnt + Na;                            // Na
    int*   gcnt   = rowptr + Na;                         // 1024
    int*   gbase  = gcnt + 1024;                         // 1028 (NB+1 used)
    int*   gcur   = gbase + 1028;                        // 1024
    int*   flagA  = gcur + 1024;                         // 4
    float* stats  = (float*)(flagA + 4);                 // 512
    float* dis    = stats + 512;                         // Na
    int*   elist  = (int*)(dis + Na);                    // Ea
    unsigned int* h1b = (unsigned int*)(elist + Ea);     // Na*64 uints (bf16x2)
    float* agg1   = (float*)(h1b + Na * 64);             // Na*128 f32
    unsigned int* ebuf = (unsigned int*)agg1;            // overlay: dead before k_agg1
    float* WT2    = agg1 + Na * 128;                     // 128*64
    uint4* Whi1   = (uint4*)(WT2 + 128 * 64);            // 2048 uint4 = 32 KB
    uint4* Wlo1   = Whi1 + 2048;                         // 32 KB
    unsigned int* h2b = h1b;                             // overlay: h1 dead after agg1

    hipMemsetAsync(gcnt, 0, 1024 * sizeof(int), stream);
    hipMemsetAsync(stats, 0, 512 * sizeof(float), stream);

    k_detect<<<1, 64, 0, stream>>>((const int*)ei, flagA);

    int gC    = (E + CHUNK - 1) / CHUNK;     // 391 chunks
    int gG1   = (N + 63) / 64;               // MFMA gemm1: 64 rows/block
    int gG2   = (N + 63) / 64;
    int gAgg  = (N + 3) / 4;

    k_prepw<<<8, 256, 0, stream>>>(W1, Whi1, Wlo1, 8);   // 2048 frag slots
    k_transpose<<<32, 256, 0, stream>>>(W2, WT2, 64);    // 8192 elems
    k_hist<<<gC, 256, 0, stream>>>(ei, flagA, gcnt, E, N, NB);
    k_scan<<<1, 1024, 0, stream>>>(gcnt, gbase, gcur, NB);
    k_scatter<<<gC, 256, 0, stream>>>(ei, flagA, gcur, ebuf, E, N, NB);
    k_fine<<<NB, 256, 0, stream>>>(ebuf, gbase, cnt, dis, rowptr, elist, N);
    k_gemm1<<<gG1, 256, 0, stream>>>(x, Whi1, Wlo1, dis, (unsigned short*)h1b, N);
    k_agg1<<<gAgg, 256, 0, stream>>>(h1b, dis, rowptr, cnt, elist, agg1, N);
    k_bnstats<<<500, 256, 0, stream>>>(agg1, stats, N);
    k_bnfin<<<1, 128, 0, stream>>>(stats, gamma, beta, N);
    k_gemm2<<<gG2, 256, 0, stream>>>(agg1, WT2, stats, dis, (uint2*)h2b, N);
    k_agg2<<<gAgg, 256, 0, stream>>>((const unsigned short*)h2b, dis, rowptr, cnt, elist, b2, out, N);
}

// Round 3
// 418.401 us; speedup vs baseline: 1.6196x; 1.0977x over previous
//
#include <hip/hip_runtime.h>

// GCNEncoder — round 13: MFMA-ize GEMM2 (same recipe as R12's GEMM1) and
// deepen gather prefetch to 16-way.
// - k_gemm2 was the last scalar-FMA GEMM (~60us, latency-bound). Now:
//   BN+ReLU applied during LDS fragment staging, exact bf16 hi/lo split,
//   mfma_f32_16x16x32_bf16, W2 pre-fragmented by k_prepw (NT=4).
//   k_transpose/WT2 deleted.
// - k_agg1/k_agg2: 16-way batched prefetch (avg deg ~16 -> one batch covers
//   most rows; 4KB in flight per wave), 8-way mid-batch, scalar tail.
// Everything else unchanged from R12.

#define SHIFT 8
#define BSZ   256          // nodes per bucket = 1<<SHIFT
#define CHUNK 4096         // edges per block in hist/scatter
#define EPT   (CHUNK/256)  // edges per thread = 16
#define NBMAX 1024         // supports N <= 262144

typedef short bf16x8 __attribute__((ext_vector_type(8)));
typedef float f32x4  __attribute__((ext_vector_type(4)));

__device__ __forceinline__ unsigned short f2bf(float f) {
    unsigned int u = __float_as_uint(f);
    unsigned int r = (u + 0x7FFFu + ((u >> 16) & 1u)) >> 16;   // RNE
    return (unsigned short)r;
}
__device__ __forceinline__ float bf2f(unsigned short h) {
    return __uint_as_float(((unsigned int)h) << 16);
}
// exact hi/lo split of a float pair, packed as bf16x2 (truncation split:
// x == bf2f(hi) + lo exactly; lo then truncated to bf16, residual ~2^-17|x|)
__device__ __forceinline__ void split2(float a, float b, unsigned int& hi, unsigned int& lo) {
    unsigned int ua = __float_as_uint(a), ub = __float_as_uint(b);
    unsigned int ha = ua & 0xFFFF0000u,  hb = ub & 0xFFFF0000u;
    hi = (ha >> 16) | hb;
    float la = a - __uint_as_float(ha);
    float lb = b - __uint_as_float(hb);
    lo = (__float_as_uint(la) >> 16) | (__float_as_uint(lb) & 0xFFFF0000u);
}

// ---------- dtype probe: edge_index may be int64 or int32 ----------
__global__ void k_detect(const int* __restrict__ ei32, int* __restrict__ flag) {
    if (threadIdx.x == 0 && blockIdx.x == 0) {
        int o = 0;
        for (int q = 0; q < 16; ++q) o |= ei32[2 * q + 1];
        flag[0] = (o == 0) ? 1 : 0;  // 1 => int64 (high dwords all zero)
    }
}

// ---------- pass 1: bucket histogram (LDS-staged) ----------
__global__ __launch_bounds__(256) void k_hist(const void* __restrict__ eiv,
                                              const int* __restrict__ flag,
                                              int* __restrict__ gcnt,
                                              int E, int N, int NB) {
    __shared__ int h[NBMAX];
    int t = threadIdx.x;
    for (int u = t; u < NB; u += 256) h[u] = 0;
    __syncthreads();
    int base = blockIdx.x * CHUNK;
    int f = flag[0];
    const long long* e64 = (const long long*)eiv;
    const int*       e32 = (const int*)eiv;
#pragma unroll
    for (int r = 0; r < EPT; ++r) {
        int e = base + r * 256 + t;
        if (e < E) {
            int s, d;
            if (f) { s = (int)e64[e]; d = (int)e64[E + e]; }
            else   { s = e32[e];      d = e32[E + e]; }
            if ((unsigned)s < (unsigned)N && (unsigned)d < (unsigned)N)
                atomicAdd(&h[d >> SHIFT], 1);
        }
    }
    __syncthreads();
    for (int u = t; u < NB; u += 256) {
        int c = h[u];
        if (c) atomicAdd(&gcnt[u], c);
    }
}

// ---------- pass 2: exclusive prefix over bucket totals ----------
__global__ void k_scan(const int* __restrict__ gcnt, int* __restrict__ gbase,
                       int* __restrict__ gcur, int NB) {
    __shared__ int sh[1024];
    int t = threadIdx.x;
    int v = (t < NB) ? gcnt[t] : 0;
    sh[t] = v;
    __syncthreads();
    for (int off = 1; off < 1024; off <<= 1) {
        int x = sh[t];
        int y = (t >= off) ? sh[t - off] : 0;
        __syncthreads();
        sh[t] = x + y;
        __syncthreads();
    }
    if (t < NB) {
        int ex = sh[t] - v;
        gbase[t] = ex;
        gcur[t]  = ex;
    }
    if (t == 0) gbase[NB] = sh[1023];
}

// ---------- pass 3: scatter edges into bucket regions, clustered ----------
__global__ __launch_bounds__(256) void k_scatter(const void* __restrict__ eiv,
                                                 const int* __restrict__ flag,
                                                 int* __restrict__ gcur,
                                                 unsigned int* __restrict__ ebuf,
                                                 int E, int N, int NB) {
    __shared__ int lcnt[NBMAX];
    __shared__ int lbase[NBMAX];
    int t = threadIdx.x;
    for (int u = t; u < NB; u += 256) lcnt[u] = 0;
    __syncthreads();
    int base = blockIdx.x * CHUNK;
    int f = flag[0];
    const long long* e64 = (const long long*)eiv;
    const int*       e32 = (const int*)eiv;
    unsigned int ent[EPT];
    int bk[EPT];
    int off[EPT];
#pragma unroll
    for (int r = 0; r < EPT; ++r) {
        int e = base + r * 256 + t;
        bk[r] = -1;
        if (e < E) {
            int s, d;
            if (f) { s = (int)e64[e]; d = (int)e64[E + e]; }
            else   { s = e32[e];      d = e32[E + e]; }
            if ((unsigned)s < (unsigned)N && (unsigned)d < (unsigned)N) {
                int b = d >> SHIFT;
                bk[r]  = b;
                off[r] = atomicAdd(&lcnt[b], 1);
                ent[r] = ((unsigned int)(d & (BSZ - 1)) << 24) | (unsigned int)s;
            }
        }
    }
    __syncthreads();
    for (int u = t; u < NB; u += 256) {
        int c = lcnt[u];
        lbase[u] = c ? atomicAdd(&gcur[u], c) : 0;
    }
    __syncthreads();
#pragma unroll
    for (int r = 0; r < EPT; ++r)
        if (bk[r] >= 0) ebuf[(size_t)lbase[bk[r]] + off[r]] = ent[r];
}

// ---------- pass 4: per-bucket CSR finalize (counts, dis, rowptr, elist) ----
__global__ __launch_bounds__(256) void k_fine(const unsigned int* __restrict__ ebuf,
                                              const int* __restrict__ gbase,
                                              int* __restrict__ cnt,
                                              float* __restrict__ dis,
                                              int* __restrict__ rowptr,
                                              int* __restrict__ elist, int N) {
    __shared__ int lc[BSZ];
    __shared__ int ls[BSZ];
    int t = threadIdx.x;
    int b = blockIdx.x;
    int start = gbase[b], end = gbase[b + 1];
    int m = end - start;
    lc[t] = 0;
    __syncthreads();
    for (int j = t; j < m; j += 256)
        atomicAdd(&lc[ebuf[start + j] >> 24], 1);
    __syncthreads();
    int v = lc[t];
    ls[t] = v;
    __syncthreads();
    for (int off = 1; off < BSZ; off <<= 1) {
        int x = ls[t];
        int y = (t >= off) ? ls[t - off] : 0;
        __syncthreads();
        ls[t] = x + y;
        __syncthreads();
    }
    int ex = ls[t] - v;
    int i = (b << SHIFT) + t;
    if (i < N) {
        cnt[i]    = v;
        dis[i]    = rsqrtf((float)v + 1.0f);
        rowptr[i] = start + ex;
    }
    lc[t] = ex;        // per-node cursor (bucket-relative)
    __syncthreads();
    for (int j = t; j < m; j += 256) {
        unsigned int e = ebuf[start + j];
        int p = atomicAdd(&lc[e >> 24], 1);
        elist[start + p] = (int)(e & 0xFFFFFFu);
    }
}

// ---------- W -> fragment-ordered bf16 hi/lo buffers ----------
// slot idx = (nt*4 + kt)*64 + lane ; lane holds B[k][n] for n = nt*16+(lane&15),
// k = kt*32 + 8*(lane>>4) + j, j=0..7 packed low-to-high (same k-map as A).
__global__ __launch_bounds__(256) void k_prepw(const float* __restrict__ W,
                                               uint4* __restrict__ Whi,
                                               uint4* __restrict__ Wlo, int NT) {
    int idx = blockIdx.x * 256 + threadIdx.x;
    if (idx >= NT * 4 * 64) return;
    int lane = idx & 63, kt = (idx >> 6) & 3, nt = idx >> 8;
    int o = nt * 16 + (lane & 15);
    int k0 = kt * 32 + (lane >> 4) * 8;
    const float* p = W + (size_t)o * 128 + k0;
    unsigned int h[4], l[4];
#pragma unroll
    for (int pr = 0; pr < 4; ++pr) split2(p[2 * pr], p[2 * pr + 1], h[pr], l[pr]);
    Whi[idx] = make_uint4(h[0], h[1], h[2], h[3]);
    Wlo[idx] = make_uint4(l[0], l[1], l[2], l[3]);
}

// ---------- GEMM1 (MFMA): h1s[n][o] (bf16) = dis[n] * (x[n]·W1[o]) ----------
__global__ __launch_bounds__(256) void k_gemm1(const float* __restrict__ x,
                                               const uint4* __restrict__ Whi,
                                               const uint4* __restrict__ Wlo,
                                               const float* __restrict__ dis,
                                               unsigned short* __restrict__ h1b, int N) {
    __shared__ uint4 Ahi[1024];   // [ (c*4+kt)*64 + lane ]
    __shared__ uint4 Alo[1024];
    int t = threadIdx.x;
    int n0 = blockIdx.x * 64;
    // ---- phase 1: x -> hi/lo fragments in LDS ----
    for (int s = t; s < 1024; s += 256) {
        int lane = s & 63, kt = (s >> 6) & 3, c = s >> 8;
        int row = n0 + c * 16 + (lane & 15);
        int rr = min(row, N - 1);
        int k0 = kt * 32 + (lane >> 4) * 8;
        const float4* p = (const float4*)(x + (size_t)rr * 128 + k0);
        float4 u0 = p[0], u1 = p[1];
        unsigned int h0, h1, h2, h3, l0, l1, l2, l3;
        split2(u0.x, u0.y, h0, l0);
        split2(u0.z, u0.w, h1, l1);
        split2(u1.x, u1.y, h2, l2);
        split2(u1.z, u1.w, h3, l3);
        Ahi[s] = make_uint4(h0, h1, h2, h3);
        Alo[s] = make_uint4(l0, l1, l2, l3);
    }
    __syncthreads();
    // ---- phase 2: MFMA ----
    int w = t >> 6, lane = t & 63;
    bf16x8 ah[4], al[4];
#pragma unroll
    for (int kt = 0; kt < 4; ++kt) {
        ah[kt] = ((const bf16x8*)Ahi)[(w * 4 + kt) * 64 + lane];
        al[kt] = ((const bf16x8*)Alo)[(w * 4 + kt) * 64 + lane];
    }
    f32x4 acc[8];
#pragma unroll
    for (int nt = 0; nt < 8; ++nt) {
        acc[nt] = (f32x4)(0.f);
#pragma unroll
        for (int kt = 0; kt < 4; ++kt) {
            bf16x8 bh = ((const bf16x8*)Whi)[(nt * 4 + kt) * 64 + lane];
            bf16x8 bl = ((const bf16x8*)Wlo)[(nt * 4 + kt) * 64 + lane];
            acc[nt] = __builtin_amdgcn_mfma_f32_16x16x32_bf16(ah[kt], bh, acc[nt], 0, 0, 0);
            acc[nt] = __builtin_amdgcn_mfma_f32_16x16x32_bf16(ah[kt], bl, acc[nt], 0, 0, 0);
            acc[nt] = __builtin_amdgcn_mfma_f32_16x16x32_bf16(al[kt], bh, acc[nt], 0, 0, 0);
        }
    }
    // ---- epilogue: scale by dis, pack bf16, store ----
    int r0 = n0 + w * 16 + (lane >> 4) * 4;
    float dv[4];
#pragma unroll
    for (int r = 0; r < 4; ++r) {
        int row = r0 + r;
        dv[r] = (row < N) ? dis[row] : 0.f;
    }
#pragma unroll
    for (int nt = 0; nt < 8; ++nt) {
        int col = nt * 16 + (lane & 15);
#pragma unroll
        for (int r = 0; r < 4; ++r) {
            int row = r0 + r;
            if (row < N) h1b[(size_t)row * 128 + col] = f2bf(dv[r] * acc[nt][r]);
        }
    }
}

// ---------- layer-1 gather: pre-scaled bf16 rows, 16-way prefetch ----------
// agg1[i] = dis_i * ( sum_edges h1s[s] + h1s[i] )
__global__ __launch_bounds__(256) void k_agg1(const unsigned int* __restrict__ h1b,
                                              const float* __restrict__ dis,
                                              const int* __restrict__ rowptr,
                                              const int* __restrict__ cnt,
                                              const int* __restrict__ elist,
                                              float* __restrict__ agg1, int N) {
    int lane = threadIdx.x & 63;
    int i = blockIdx.x * 4 + (threadIdx.x >> 6);
    if (i >= N) return;
    float accx = 0.f, accy = 0.f;
    int base = rowptr[i], c = cnt[i];
    int j = 0;
    for (; j + 16 <= c; j += 16) {
        int ss[16];
#pragma unroll
        for (int r = 0; r < 16; ++r) ss[r] = elist[base + j + r];
        unsigned int vv[16];
#pragma unroll
        for (int r = 0; r < 16; ++r) vv[r] = h1b[(size_t)ss[r] * 64 + lane];  // 256B/row
#pragma unroll
        for (int r = 0; r < 16; ++r) {
            accx += bf2f((unsigned short)(vv[r] & 0xFFFF));
            accy += bf2f((unsigned short)(vv[r] >> 16));
        }
    }
    if (j + 8 <= c) {
        int ss[8];
#pragma unroll
        for (int r = 0; r < 8; ++r) ss[r] = elist[base + j + r];
        unsigned int vv[8];
#pragma unroll
        for (int r = 0; r < 8; ++r) vv[r] = h1b[(size_t)ss[r] * 64 + lane];
#pragma unroll
        for (int r = 0; r < 8; ++r) {
            accx += bf2f((unsigned short)(vv[r] & 0xFFFF));
            accy += bf2f((unsigned short)(vv[r] >> 16));
        }
        j += 8;
    }
    for (; j < c; ++j) {
        int s = elist[base + j];
        unsigned int v = h1b[(size_t)s * 64 + lane];
        accx += bf2f((unsigned short)(v & 0xFFFF));
        accy += bf2f((unsigned short)(v >> 16));
    }
    float di = dis[i];
    unsigned int sv = h1b[(size_t)i * 64 + lane];
    float2 r;
    r.x = di * (accx + bf2f((unsigned short)(sv & 0xFFFF)));
    r.y = di * (accy + bf2f((unsigned short)(sv >> 16)));
    ((float2*)agg1)[(size_t)i * 64 + lane] = r;
}

// ---------- BN stats (proven, fp32 agg1) ----------
__global__ __launch_bounds__(256) void k_bnstats(const float* __restrict__ agg1,
                                                 float* __restrict__ stats, int N) {
    int t = threadIdx.x;
    int f = t & 127, half = t >> 7;
    float s = 0.f, sq = 0.f;
    int stride = gridDim.x * 2;
    for (int r = blockIdx.x * 2 + half; r < N; r += stride) {
        float v = agg1[r * 128 + f];
        s += v; sq += v * v;
    }
    __shared__ float ls[256], lq[256];
    ls[t] = s; lq[t] = sq;
    __syncthreads();
    if (t < 128) {
        atomicAdd(&stats[f], ls[t] + ls[t + 128]);
        atomicAdd(&stats[128 + f], lq[t] + lq[t + 128]);
    }
}

// ---------- BN finalize (proven) ----------
__global__ void k_bnfin(float* __restrict__ stats, const float* __restrict__ gamma,
                        const float* __restrict__ beta, int N) {
    int f = threadIdx.x;
    if (f >= 128) return;
    float invN = 1.0f / (float)N;
    float mean = stats[f] * invN;
    float var = stats[128 + f] * invN - mean * mean;
    var = fmaxf(var, 0.f);
    float inv = rsqrtf(var + 1e-5f);
    float sc = gamma[f] * inv;
    stats[256 + f] = sc;
    stats[384 + f] = beta[f] - mean * sc;
}

// ---------- GEMM2 (MFMA): h2s[n][o] (bf16) = dis[n]*(relu(bn(agg1[n]))·W2[o])
// Same structure as k_gemm1; BN+ReLU applied during LDS fragment staging.
__global__ __launch_bounds__(256) void k_gemm2(const float* __restrict__ agg1,
                                               const uint4* __restrict__ Whi,
                                               const uint4* __restrict__ Wlo,
                                               const float* __restrict__ stats,
                                               const float* __restrict__ dis,
                                               unsigned short* __restrict__ h2b, int N) {
    __shared__ uint4 Ahi[1024];   // [ (c*4+kt)*64 + lane ]
    __shared__ uint4 Alo[1024];
    int t = threadIdx.x;
    int n0 = blockIdx.x * 64;
    const float4* st = (const float4*)stats;
    // ---- phase 1: relu(bn(agg1)) -> hi/lo fragments in LDS ----
    for (int s = t; s < 1024; s += 256) {
        int lane = s & 63, kt = (s >> 6) & 3, c = s >> 8;
        int row = n0 + c * 16 + (lane & 15);
        int rr = min(row, N - 1);
        int k0 = kt * 32 + (lane >> 4) * 8;
        const float4* p = (const float4*)(agg1 + (size_t)rr * 128 + k0);
        float4 a0 = p[0], a1 = p[1];
        float4 c0 = st[64 + (k0 >> 2)], c1 = st[65 + (k0 >> 2)];
        float4 s0 = st[96 + (k0 >> 2)], s1 = st[97 + (k0 >> 2)];
        float v0 = fmaxf(a0.x * c0.x + s0.x, 0.f);
        float v1 = fmaxf(a0.y * c0.y + s0.y, 0.f);
        float v2 = fmaxf(a0.z * c0.z + s0.z, 0.f);
        float v3 = fmaxf(a0.w * c0.w + s0.w, 0.f);
        float v4 = fmaxf(a1.x * c1.x + s1.x, 0.f);
        float v5 = fmaxf(a1.y * c1.y + s1.y, 0.f);
        float v6 = fmaxf(a1.z * c1.z + s1.z, 0.f);
        float v7 = fmaxf(a1.w * c1.w + s1.w, 0.f);
        unsigned int h0, h1, h2, h3, l0, l1, l2, l3;
        split2(v0, v1, h0, l0);
        split2(v2, v3, h1, l1);
        split2(v4, v5, h2, l2);
        split2(v6, v7, h3, l3);
        Ahi[s] = make_uint4(h0, h1, h2, h3);
        Alo[s] = make_uint4(l0, l1, l2, l3);
    }
    __syncthreads();
    // ---- phase 2: MFMA (4 nt x 4 kt x 3) ----
    int w = t >> 6, lane = t & 63;
    bf16x8 ah[4], al[4];
#pragma unroll
    for (int kt = 0; kt < 4; ++kt) {
        ah[kt] = ((const bf16x8*)Ahi)[(w * 4 + kt) * 64 + lane];
        al[kt] = ((const bf16x8*)Alo)[(w * 4 + kt) * 64 + lane];
    }
    f32x4 acc[4];
#pragma unroll
    for (int nt = 0; nt < 4; ++nt) {
        acc[nt] = (f32x4)(0.f);
#pragma unroll
        for (int kt = 0; kt < 4; ++kt) {
            bf16x8 bh = ((const bf16x8*)Whi)[(nt * 4 + kt) * 64 + lane];
            bf16x8 bl = ((const bf16x8*)Wlo)[(nt * 4 + kt) * 64 + lane];
            acc[nt] = __builtin_amdgcn_mfma_f32_16x16x32_bf16(ah[kt], bh, acc[nt], 0, 0, 0);
            acc[nt] = __builtin_amdgcn_mfma_f32_16x16x32_bf16(ah[kt], bl, acc[nt], 0, 0, 0);
            acc[nt] = __builtin_amdgcn_mfma_f32_16x16x32_bf16(al[kt], bh, acc[nt], 0, 0, 0);
        }
    }
    // ---- epilogue: scale by dis, pack bf16, store (64 cols) ----
    int r0 = n0 + w * 16 + (lane >> 4) * 4;
    float dv[4];
#pragma unroll
    for (int r = 0; r < 4; ++r) {
        int row = r0 + r;
        dv[r] = (row < N) ? dis[row] : 0.f;
    }
#pragma unroll
    for (int nt = 0; nt < 4; ++nt) {
        int col = nt * 16 + (lane & 15);
#pragma unroll
        for (int r = 0; r < 4; ++r) {
            int row = r0 + r;
            if (row < N) h2b[(size_t)row * 64 + col] = f2bf(dv[r] * acc[nt][r]);
        }
    }
}

// ---------- layer-2 gather: pre-scaled bf16 rows, 16-way prefetch ----------
// out[i] = dis_i * ( sum_edges h2s[s] + h2s[i] ) + b2
__global__ __launch_bounds__(256) void k_agg2(const unsigned short* __restrict__ h2b,
                                              const float* __restrict__ dis,
                                              const int* __restrict__ rowptr,
                                              const int* __restrict__ cnt,
                                              const int* __restrict__ elist,
                                              const float* __restrict__ b2,
                                              float* __restrict__ out, int N) {
    int lane = threadIdx.x & 63;
    int i = blockIdx.x * 4 + (threadIdx.x >> 6);
    if (i >= N) return;
    float acc = 0.f;
    int base = rowptr[i], c = cnt[i];
    int j = 0;
    for (; j + 16 <= c; j += 16) {
        int ss[16];
#pragma unroll
        for (int r = 0; r < 16; ++r) ss[r] = elist[base + j + r];
        unsigned short vv[16];
#pragma unroll
        for (int r = 0; r < 16; ++r) vv[r] = h2b[(size_t)ss[r] * 64 + lane];  // 128B/row
#pragma unroll
        for (int r = 0; r < 16; ++r) acc += bf2f(vv[r]);
    }
    if (j + 8 <= c) {
        int ss[8];
#pragma unroll
        for (int r = 0; r < 8; ++r) ss[r] = elist[base + j + r];
        unsigned short vv[8];
#pragma unroll
        for (int r = 0; r < 8; ++r) vv[r] = h2b[(size_t)ss[r] * 64 + lane];
#pragma unroll
        for (int r = 0; r < 8; ++r) acc += bf2f(vv[r]);
        j += 8;
    }
    for (; j < c; ++j) {
        int s = elist[base + j];
        acc += bf2f(h2b[(size_t)s * 64 + lane]);
    }
    float di = dis[i];
    float self = bf2f(h2b[(size_t)i * 64 + lane]);
    out[(size_t)i * 64 + lane] = di * (acc + self) + b2[lane];
}

extern "C" void kernel_launch(void* const* d_in, const int* in_sizes, int n_in,
                              void* d_out, int out_size, void* d_ws, size_t ws_size,
                              hipStream_t stream) {
    const float* x     = (const float*)d_in[0];
    const void*  ei    = d_in[1];            // int64 or int32, probed on device
    const float* W1    = (const float*)d_in[2];
    // d_in[3] = b1: cancels exactly through BatchNorm -> skipped
    const float* gamma = (const float*)d_in[4];
    const float* beta  = (const float*)d_in[5];
    const float* W2    = (const float*)d_in[6];
    const float* b2    = (const float*)d_in[7];
    float* out = (float*)d_out;

    int N = in_sizes[0] / 128;
    int E = in_sizes[1] / 2;
    int NB = (N + BSZ - 1) >> SHIFT;         // 391 buckets for N=100000 (<= NBMAX)

    // ---- workspace layout (~85 MB; all regions 16B-aligned) ----
    size_t Na = ((size_t)N + 3) & ~(size_t)3;
    size_t Ea = ((size_t)E + 3) & ~(size_t)3;
    int*   cnt    = (int*)d_ws;                          // Na
    int*   rowptr = cnt + Na;                            // Na
    int*   gcnt   = rowptr + Na;                         // 1024
    int*   gbase  = gcnt + 1024;                         // 1028 (NB+1 used)
    int*   gcur   = gbase + 1028;                        // 1024
    int*   flagA  = gcur + 1024;                         // 4
    float* stats  = (float*)(flagA + 4);                 // 512
    float* dis    = stats + 512;                         // Na
    int*   elist  = (int*)(dis + Na);                    // Ea
    unsigned int* h1b = (unsigned int*)(elist + Ea);     // Na*64 uints (bf16x2)
    float* agg1   = (float*)(h1b + Na * 64);             // Na*128 f32
    unsigned int* ebuf = (unsigned int*)agg1;            // overlay: dead before k_agg1
    uint4* Whi1   = (uint4*)(agg1 + Na * 128);           // 2048 uint4 = 32 KB
    uint4* Wlo1   = Whi1 + 2048;                         // 32 KB
    uint4* Whi2   = Wlo1 + 2048;                         // 1024 uint4 = 16 KB
    uint4* Wlo2   = Whi2 + 1024;                         // 16 KB
    unsigned int* h2b = h1b;                             // overlay: h1 dead after agg1

    hipMemsetAsync(gcnt, 0, 1024 * sizeof(int), stream);
    hipMemsetAsync(stats, 0, 512 * sizeof(float), stream);

    k_detect<<<1, 64, 0, stream>>>((const int*)ei, flagA);

    int gC    = (E + CHUNK - 1) / CHUNK;     // 391 chunks
    int gG1   = (N + 63) / 64;               // MFMA gemms: 64 rows/block
    int gAgg  = (N + 3) / 4;

    k_prepw<<<8, 256, 0, stream>>>(W1, Whi1, Wlo1, 8);   // 2048 frag slots
    k_prepw<<<4, 256, 0, stream>>>(W2, Whi2, Wlo2, 4);   // 1024 frag slots
    k_hist<<<gC, 256, 0, stream>>>(ei, flagA, gcnt, E, N, NB);
    k_scan<<<1, 1024, 0, stream>>>(gcnt, gbase, gcur, NB);
    k_scatter<<<gC, 256, 0, stream>>>(ei, flagA, gcur, ebuf, E, N, NB);
    k_fine<<<NB, 256, 0, stream>>>(ebuf, gbase, cnt, dis, rowptr, elist, N);
    k_gemm1<<<gG1, 256, 0, stream>>>(x, Whi1, Wlo1, dis, (unsigned short*)h1b, N);
    k_agg1<<<gAgg, 256, 0, stream>>>(h1b, dis, rowptr, cnt, elist, agg1, N);
    k_bnstats<<<500, 256, 0, stream>>>(agg1, stats, N);
    k_bnfin<<<1, 128, 0, stream>>>(stats, gamma, beta, N);
    k_gemm2<<<gG1, 256, 0, stream>>>(agg1, Whi2, Wlo2, stats, dis, (unsigned short*)h2b, N);
    k_agg2<<<gAgg, 256, 0, stream>>>((const unsigned short*)h2b, dis, rowptr, cnt, elist, b2, out, N);
}

// Round 4
// 399.114 us; speedup vs baseline: 1.6979x; 1.0483x over previous
//
#include <hip/hip_runtime.h>

// GCNEncoder — round 14: consolidation.
// - BN stats fused into k_agg1 (LDS block-reduce -> 256-way-sliced atomic
//   partials spart[bid&255][256]; ~100 atomics/address, no contention).
//   k_bnstats (51 MB re-read, ~14us) deleted; k_bnfin reduces spart (~3us).
// - k_detect deleted: k_hist/k_scatter compute the int64/int32 flag locally
//   (16 L2-hot loads per block).
// - k_prepw: single launch converts both W1 and W2.
// Gathers/GEMMs unchanged from R13 (16-way prefetch was a null vs 8-way:
// k_agg1 is L2-miss-path bound, not latency bound).

#define SHIFT 8
#define BSZ   256          // nodes per bucket = 1<<SHIFT
#define CHUNK 4096         // edges per block in hist/scatter
#define EPT   (CHUNK/256)  // edges per thread = 16
#define NBMAX 1024         // supports N <= 262144

typedef short bf16x8 __attribute__((ext_vector_type(8)));
typedef float f32x4  __attribute__((ext_vector_type(4)));

__device__ __forceinline__ unsigned short f2bf(float f) {
    unsigned int u = __float_as_uint(f);
    unsigned int r = (u + 0x7FFFu + ((u >> 16) & 1u)) >> 16;   // RNE
    return (unsigned short)r;
}
__device__ __forceinline__ float bf2f(unsigned short h) {
    return __uint_as_float(((unsigned int)h) << 16);
}
// exact hi/lo split of a float pair, packed as bf16x2 (truncation split:
// x == bf2f(hi) + lo exactly; lo then truncated to bf16, residual ~2^-17|x|)
__device__ __forceinline__ void split2(float a, float b, unsigned int& hi, unsigned int& lo) {
    unsigned int ua = __float_as_uint(a), ub = __float_as_uint(b);
    unsigned int ha = ua & 0xFFFF0000u,  hb = ub & 0xFFFF0000u;
    hi = (ha >> 16) | hb;
    float la = a - __uint_as_float(ha);
    float lb = b - __uint_as_float(hb);
    lo = (__float_as_uint(la) >> 16) | (__float_as_uint(lb) & 0xFFFF0000u);
}
// dtype probe, computed per-block (reads 16 L2-hot ints): 1 => int64 input
__device__ __forceinline__ int detect64(const int* __restrict__ p) {
    int o = 0;
#pragma unroll
    for (int q = 0; q < 16; ++q) o |= p[2 * q + 1];
    return (o == 0) ? 1 : 0;
}

// ---------- pass 1: bucket histogram (LDS-staged) ----------
__global__ __launch_bounds__(256) void k_hist(const void* __restrict__ eiv,
                                              int* __restrict__ gcnt,
                                              int E, int N, int NB) {
    __shared__ int h[NBMAX];
    int t = threadIdx.x;
    for (int u = t; u < NB; u += 256) h[u] = 0;
    __syncthreads();
    int base = blockIdx.x * CHUNK;
    int f = detect64((const int*)eiv);
    const long long* e64 = (const long long*)eiv;
    const int*       e32 = (const int*)eiv;
#pragma unroll
    for (int r = 0; r < EPT; ++r) {
        int e = base + r * 256 + t;
        if (e < E) {
            int s, d;
            if (f) { s = (int)e64[e]; d = (int)e64[E + e]; }
            else   { s = e32[e];      d = e32[E + e]; }
            if ((unsigned)s < (unsigned)N && (unsigned)d < (unsigned)N)
                atomicAdd(&h[d >> SHIFT], 1);
        }
    }
    __syncthreads();
    for (int u = t; u < NB; u += 256) {
        int c = h[u];
        if (c) atomicAdd(&gcnt[u], c);
    }
}

// ---------- pass 2: exclusive prefix over bucket totals ----------
__global__ void k_scan(const int* __restrict__ gcnt, int* __restrict__ gbase,
                       int* __restrict__ gcur, int NB) {
    __shared__ int sh[1024];
    int t = threadIdx.x;
    int v = (t < NB) ? gcnt[t] : 0;
    sh[t] = v;
    __syncthreads();
    for (int off = 1; off < 1024; off <<= 1) {
        int x = sh[t];
        int y = (t >= off) ? sh[t - off] : 0;
        __syncthreads();
        sh[t] = x + y;
        __syncthreads();
    }
    if (t < NB) {
        int ex = sh[t] - v;
        gbase[t] = ex;
        gcur[t]  = ex;
    }
    if (t == 0) gbase[NB] = sh[1023];
}

// ---------- pass 3: scatter edges into bucket regions, clustered ----------
__global__ __launch_bounds__(256) void k_scatter(const void* __restrict__ eiv,
                                                 int* __restrict__ gcur,
                                                 unsigned int* __restrict__ ebuf,
                                                 int E, int N, int NB) {
    __shared__ int lcnt[NBMAX];
    __shared__ int lbase[NBMAX];
    int t = threadIdx.x;
    for (int u = t; u < NB; u += 256) lcnt[u] = 0;
    __syncthreads();
    int base = blockIdx.x * CHUNK;
    int f = detect64((const int*)eiv);
    const long long* e64 = (const long long*)eiv;
    const int*       e32 = (const int*)eiv;
    unsigned int ent[EPT];
    int bk[EPT];
    int off[EPT];
#pragma unroll
    for (int r = 0; r < EPT; ++r) {
        int e = base + r * 256 + t;
        bk[r] = -1;
        if (e < E) {
            int s, d;
            if (f) { s = (int)e64[e]; d = (int)e64[E + e]; }
            else   { s = e32[e];      d = e32[E + e]; }
            if ((unsigned)s < (unsigned)N && (unsigned)d < (unsigned)N) {
                int b = d >> SHIFT;
                bk[r]  = b;
                off[r] = atomicAdd(&lcnt[b], 1);
                ent[r] = ((unsigned int)(d & (BSZ - 1)) << 24) | (unsigned int)s;
            }
        }
    }
    __syncthreads();
    for (int u = t; u < NB; u += 256) {
        int c = lcnt[u];
        lbase[u] = c ? atomicAdd(&gcur[u], c) : 0;
    }
    __syncthreads();
#pragma unroll
    for (int r = 0; r < EPT; ++r)
        if (bk[r] >= 0) ebuf[(size_t)lbase[bk[r]] + off[r]] = ent[r];
}

// ---------- pass 4: per-bucket CSR finalize (counts, dis, rowptr, elist) ----
__global__ __launch_bounds__(256) void k_fine(const unsigned int* __restrict__ ebuf,
                                              const int* __restrict__ gbase,
                                              int* __restrict__ cnt,
                                              float* __restrict__ dis,
                                              int* __restrict__ rowptr,
                                              int* __restrict__ elist, int N) {
    __shared__ int lc[BSZ];
    __shared__ int ls[BSZ];
    int t = threadIdx.x;
    int b = blockIdx.x;
    int start = gbase[b], end = gbase[b + 1];
    int m = end - start;
    lc[t] = 0;
    __syncthreads();
    for (int j = t; j < m; j += 256)
        atomicAdd(&lc[ebuf[start + j] >> 24], 1);
    __syncthreads();
    int v = lc[t];
    ls[t] = v;
    __syncthreads();
    for (int off = 1; off < BSZ; off <<= 1) {
        int x = ls[t];
        int y = (t >= off) ? ls[t - off] : 0;
        __syncthreads();
        ls[t] = x + y;
        __syncthreads();
    }
    int ex = ls[t] - v;
    int i = (b << SHIFT) + t;
    if (i < N) {
        cnt[i]    = v;
        dis[i]    = rsqrtf((float)v + 1.0f);
        rowptr[i] = start + ex;
    }
    lc[t] = ex;        // per-node cursor (bucket-relative)
    __syncthreads();
    for (int j = t; j < m; j += 256) {
        unsigned int e = ebuf[start + j];
        int p = atomicAdd(&lc[e >> 24], 1);
        elist[start + p] = (int)(e & 0xFFFFFFu);
    }
}

// ---------- W1+W2 -> fragment-ordered bf16 hi/lo buffers (one launch) ------
// slot = (nt*4 + kt)*64 + lane ; lane holds B[k][n] for n = nt*16+(lane&15),
// k = kt*32 + 8*(lane>>4) + j, j=0..7 packed low-to-high (same k-map as A).
__global__ __launch_bounds__(256) void k_prepw(const float* __restrict__ W1,
                                               const float* __restrict__ W2,
                                               uint4* __restrict__ Whi1,
                                               uint4* __restrict__ Wlo1,
                                               uint4* __restrict__ Whi2,
                                               uint4* __restrict__ Wlo2) {
    int idx = blockIdx.x * 256 + threadIdx.x;
    const float* W; uint4 *H, *L; int slot;
    if (idx < 2048)      { W = W1; H = Whi1; L = Wlo1; slot = idx; }
    else if (idx < 3072) { W = W2; H = Whi2; L = Wlo2; slot = idx - 2048; }
    else return;
    int lane = slot & 63, kt = (slot >> 6) & 3, nt = slot >> 8;
    int o = nt * 16 + (lane & 15);
    int k0 = kt * 32 + (lane >> 4) * 8;
    const float* p = W + (size_t)o * 128 + k0;
    unsigned int h[4], l[4];
#pragma unroll
    for (int pr = 0; pr < 4; ++pr) split2(p[2 * pr], p[2 * pr + 1], h[pr], l[pr]);
    H[slot] = make_uint4(h[0], h[1], h[2], h[3]);
    L[slot] = make_uint4(l[0], l[1], l[2], l[3]);
}

// ---------- GEMM1 (MFMA): h1s[n][o] (bf16) = dis[n] * (x[n]·W1[o]) ----------
__global__ __launch_bounds__(256) void k_gemm1(const float* __restrict__ x,
                                               const uint4* __restrict__ Whi,
                                               const uint4* __restrict__ Wlo,
                                               const float* __restrict__ dis,
                                               unsigned short* __restrict__ h1b, int N) {
    __shared__ uint4 Ahi[1024];   // [ (c*4+kt)*64 + lane ]
    __shared__ uint4 Alo[1024];
    int t = threadIdx.x;
    int n0 = blockIdx.x * 64;
    // ---- phase 1: x -> hi/lo fragments in LDS ----
    for (int s = t; s < 1024; s += 256) {
        int lane = s & 63, kt = (s >> 6) & 3, c = s >> 8;
        int row = n0 + c * 16 + (lane & 15);
        int rr = min(row, N - 1);
        int k0 = kt * 32 + (lane >> 4) * 8;
        const float4* p = (const float4*)(x + (size_t)rr * 128 + k0);
        float4 u0 = p[0], u1 = p[1];
        unsigned int h0, h1, h2, h3, l0, l1, l2, l3;
        split2(u0.x, u0.y, h0, l0);
        split2(u0.z, u0.w, h1, l1);
        split2(u1.x, u1.y, h2, l2);
        split2(u1.z, u1.w, h3, l3);
        Ahi[s] = make_uint4(h0, h1, h2, h3);
        Alo[s] = make_uint4(l0, l1, l2, l3);
    }
    __syncthreads();
    // ---- phase 2: MFMA ----
    int w = t >> 6, lane = t & 63;
    bf16x8 ah[4], al[4];
#pragma unroll
    for (int kt = 0; kt < 4; ++kt) {
        ah[kt] = ((const bf16x8*)Ahi)[(w * 4 + kt) * 64 + lane];
        al[kt] = ((const bf16x8*)Alo)[(w * 4 + kt) * 64 + lane];
    }
    f32x4 acc[8];
#pragma unroll
    for (int nt = 0; nt < 8; ++nt) {
        acc[nt] = (f32x4)(0.f);
#pragma unroll
        for (int kt = 0; kt < 4; ++kt) {
            bf16x8 bh = ((const bf16x8*)Whi)[(nt * 4 + kt) * 64 + lane];
            bf16x8 bl = ((const bf16x8*)Wlo)[(nt * 4 + kt) * 64 + lane];
            acc[nt] = __builtin_amdgcn_mfma_f32_16x16x32_bf16(ah[kt], bh, acc[nt], 0, 0, 0);
            acc[nt] = __builtin_amdgcn_mfma_f32_16x16x32_bf16(ah[kt], bl, acc[nt], 0, 0, 0);
            acc[nt] = __builtin_amdgcn_mfma_f32_16x16x32_bf16(al[kt], bh, acc[nt], 0, 0, 0);
        }
    }
    // ---- epilogue: scale by dis, pack bf16, store ----
    int r0 = n0 + w * 16 + (lane >> 4) * 4;
    float dv[4];
#pragma unroll
    for (int r = 0; r < 4; ++r) {
        int row = r0 + r;
        dv[r] = (row < N) ? dis[row] : 0.f;
    }
#pragma unroll
    for (int nt = 0; nt < 8; ++nt) {
        int col = nt * 16 + (lane & 15);
#pragma unroll
        for (int r = 0; r < 4; ++r) {
            int row = r0 + r;
            if (row < N) h1b[(size_t)row * 128 + col] = f2bf(dv[r] * acc[nt][r]);
        }
    }
}

// ---------- layer-1 gather + fused BN-stats ----------
// agg1[i] = dis_i * ( sum_edges h1s[s] + h1s[i] ); block-reduced sums/sumsqs
// atomically added into spart[blockIdx&255][256] (sliced -> no contention).
__global__ __launch_bounds__(256) void k_agg1(const unsigned int* __restrict__ h1b,
                                              const float* __restrict__ dis,
                                              const int* __restrict__ rowptr,
                                              const int* __restrict__ cnt,
                                              const int* __restrict__ elist,
                                              float* __restrict__ agg1,
                                              float* __restrict__ spart, int N) {
    int t = threadIdx.x;
    int lane = t & 63;
    int i = blockIdx.x * 4 + (t >> 6);
    bool act = (i < N);
    float accx = 0.f, accy = 0.f;
    int base = 0, c = 0;
    if (act) { base = rowptr[i]; c = cnt[i]; }
    int j = 0;
    for (; j + 16 <= c; j += 16) {
        int ss[16];
#pragma unroll
        for (int r = 0; r < 16; ++r) ss[r] = elist[base + j + r];
        unsigned int vv[16];
#pragma unroll
        for (int r = 0; r < 16; ++r) vv[r] = h1b[(size_t)ss[r] * 64 + lane];  // 256B/row
#pragma unroll
        for (int r = 0; r < 16; ++r) {
            accx += bf2f((unsigned short)(vv[r] & 0xFFFF));
            accy += bf2f((unsigned short)(vv[r] >> 16));
        }
    }
    if (j + 8 <= c) {
        int ss[8];
#pragma unroll
        for (int r = 0; r < 8; ++r) ss[r] = elist[base + j + r];
        unsigned int vv[8];
#pragma unroll
        for (int r = 0; r < 8; ++r) vv[r] = h1b[(size_t)ss[r] * 64 + lane];
#pragma unroll
        for (int r = 0; r < 8; ++r) {
            accx += bf2f((unsigned short)(vv[r] & 0xFFFF));
            accy += bf2f((unsigned short)(vv[r] >> 16));
        }
        j += 8;
    }
    for (; j < c; ++j) {
        int s = elist[base + j];
        unsigned int v = h1b[(size_t)s * 64 + lane];
        accx += bf2f((unsigned short)(v & 0xFFFF));
        accy += bf2f((unsigned short)(v >> 16));
    }
    float rx = 0.f, ry = 0.f;
    if (act) {
        float di = dis[i];
        unsigned int sv = h1b[(size_t)i * 64 + lane];
        rx = di * (accx + bf2f((unsigned short)(sv & 0xFFFF)));
        ry = di * (accy + bf2f((unsigned short)(sv >> 16)));
        ((float2*)agg1)[(size_t)i * 64 + lane] = make_float2(rx, ry);
    }
    // ---- fused BN partial stats: features 2*lane, 2*lane+1 per node ----
    __shared__ float4 red[256];
    red[t] = make_float4(rx, ry, rx * rx, ry * ry);
    __syncthreads();
    if (t < 64) {
        float4 a = red[t], b = red[t + 64], cc = red[t + 128], d = red[t + 192];
        float sx = a.x + b.x + cc.x + d.x;
        float sy = a.y + b.y + cc.y + d.y;
        float qx = a.z + b.z + cc.z + d.z;
        float qy = a.w + b.w + cc.w + d.w;
        float* sp = spart + ((size_t)(blockIdx.x & 255) << 8);
        atomicAdd(&sp[2 * t],       sx);
        atomicAdd(&sp[2 * t + 1],   sy);
        atomicAdd(&sp[128 + 2 * t],     qx);
        atomicAdd(&sp[128 + 2 * t + 1], qy);
    }
}

// ---------- BN finalize: reduce spart slices, then scale/shift ----------
__global__ void k_bnfin(const float* __restrict__ spart, float* __restrict__ stats,
                        const float* __restrict__ gamma,
                        const float* __restrict__ beta, int N) {
    __shared__ float sred[256];
    int t = threadIdx.x;   // 256 threads
    float s = 0.f;
    for (int sl = 0; sl < 256; ++sl) s += spart[sl * 256 + t];
    sred[t] = s;
    __syncthreads();
    if (t < 128) {
        float invN = 1.0f / (float)N;
        float mean = sred[t] * invN;
        float var = sred[128 + t] * invN - mean * mean;
        var = fmaxf(var, 0.f);
        float inv = rsqrtf(var + 1e-5f);
        float sc = gamma[t] * inv;
        stats[256 + t] = sc;
        stats[384 + t] = beta[t] - mean * sc;
    }
}

// ---------- GEMM2 (MFMA): h2s[n][o] (bf16) = dis[n]*(relu(bn(agg1[n]))·W2[o])
// Same structure as k_gemm1; BN+ReLU applied during LDS fragment staging.
__global__ __launch_bounds__(256) void k_gemm2(const float* __restrict__ agg1,
                                               const uint4* __restrict__ Whi,
                                               const uint4* __restrict__ Wlo,
                                               const float* __restrict__ stats,
                                               const float* __restrict__ dis,
                                               unsigned short* __restrict__ h2b, int N) {
    __shared__ uint4 Ahi[1024];   // [ (c*4+kt)*64 + lane ]
    __shared__ uint4 Alo[1024];
    int t = threadIdx.x;
    int n0 = blockIdx.x * 64;
    const float4* st = (const float4*)stats;
    // ---- phase 1: relu(bn(agg1)) -> hi/lo fragments in LDS ----
    for (int s = t; s < 1024; s += 256) {
        int lane = s & 63, kt = (s >> 6) & 3, c = s >> 8;
        int row = n0 + c * 16 + (lane & 15);
        int rr = min(row, N - 1);
        int k0 = kt * 32 + (lane >> 4) * 8;
        const float4* p = (const float4*)(agg1 + (size_t)rr * 128 + k0);
        float4 a0 = p[0], a1 = p[1];
        float4 c0 = st[64 + (k0 >> 2)], c1 = st[65 + (k0 >> 2)];
        float4 s0 = st[96 + (k0 >> 2)], s1 = st[97 + (k0 >> 2)];
        float v0 = fmaxf(a0.x * c0.x + s0.x, 0.f);
        float v1 = fmaxf(a0.y * c0.y + s0.y, 0.f);
        float v2 = fmaxf(a0.z * c0.z + s0.z, 0.f);
        float v3 = fmaxf(a0.w * c0.w + s0.w, 0.f);
        float v4 = fmaxf(a1.x * c1.x + s1.x, 0.f);
        float v5 = fmaxf(a1.y * c1.y + s1.y, 0.f);
        float v6 = fmaxf(a1.z * c1.z + s1.z, 0.f);
        float v7 = fmaxf(a1.w * c1.w + s1.w, 0.f);
        unsigned int h0, h1, h2, h3, l0, l1, l2, l3;
        split2(v0, v1, h0, l0);
        split2(v2, v3, h1, l1);
        split2(v4, v5, h2, l2);
        split2(v6, v7, h3, l3);
        Ahi[s] = make_uint4(h0, h1, h2, h3);
        Alo[s] = make_uint4(l0, l1, l2, l3);
    }
    __syncthreads();
    // ---- phase 2: MFMA (4 nt x 4 kt x 3) ----
    int w = t >> 6, lane = t & 63;
    bf16x8 ah[4], al[4];
#pragma unroll
    for (int kt = 0; kt < 4; ++kt) {
        ah[kt] = ((const bf16x8*)Ahi)[(w * 4 + kt) * 64 + lane];
        al[kt] = ((const bf16x8*)Alo)[(w * 4 + kt) * 64 + lane];
    }
    f32x4 acc[4];
#pragma unroll
    for (int nt = 0; nt < 4; ++nt) {
        acc[nt] = (f32x4)(0.f);
#pragma unroll
        for (int kt = 0; kt < 4; ++kt) {
            bf16x8 bh = ((const bf16x8*)Whi)[(nt * 4 + kt) * 64 + lane];
            bf16x8 bl = ((const bf16x8*)Wlo)[(nt * 4 + kt) * 64 + lane];
            acc[nt] = __builtin_amdgcn_mfma_f32_16x16x32_bf16(ah[kt], bh, acc[nt], 0, 0, 0);
            acc[nt] = __builtin_amdgcn_mfma_f32_16x16x32_bf16(ah[kt], bl, acc[nt], 0, 0, 0);
            acc[nt] = __builtin_amdgcn_mfma_f32_16x16x32_bf16(al[kt], bh, acc[nt], 0, 0, 0);
        }
    }
    // ---- epilogue: scale by dis, pack bf16, store (64 cols) ----
    int r0 = n0 + w * 16 + (lane >> 4) * 4;
    float dv[4];
#pragma unroll
    for (int r = 0; r < 4; ++r) {
        int row = r0 + r;
        dv[r] = (row < N) ? dis[row] : 0.f;
    }
#pragma unroll
    for (int nt = 0; nt < 4; ++nt) {
        int col = nt * 16 + (lane & 15);
#pragma unroll
        for (int r = 0; r < 4; ++r) {
            int row = r0 + r;
            if (row < N) h2b[(size_t)row * 64 + col] = f2bf(dv[r] * acc[nt][r]);
        }
    }
}

// ---------- layer-2 gather: pre-scaled bf16 rows, 16-way prefetch ----------
// out[i] = dis_i * ( sum_edges h2s[s] + h2s[i] ) + b2
__global__ __launch_bounds__(256) void k_agg2(const unsigned short* __restrict__ h2b,
                                              const float* __restrict__ dis,
                                              const int* __restrict__ rowptr,
                                              const int* __restrict__ cnt,
                                              const int* __restrict__ elist,
                                              const float* __restrict__ b2,
                                              float* __restrict__ out, int N) {
    int lane = threadIdx.x & 63;
    int i = blockIdx.x * 4 + (threadIdx.x >> 6);
    if (i >= N) return;
    float acc = 0.f;
    int base = rowptr[i], c = cnt[i];
    int j = 0;
    for (; j + 16 <= c; j += 16) {
        int ss[16];
#pragma unroll
        for (int r = 0; r < 16; ++r) ss[r] = elist[base + j + r];
        unsigned short vv[16];
#pragma unroll
        for (int r = 0; r < 16; ++r) vv[r] = h2b[(size_t)ss[r] * 64 + lane];  // 128B/row
#pragma unroll
        for (int r = 0; r < 16; ++r) acc += bf2f(vv[r]);
    }
    if (j + 8 <= c) {
        int ss[8];
#pragma unroll
        for (int r = 0; r < 8; ++r) ss[r] = elist[base + j + r];
        unsigned short vv[8];
#pragma unroll
        for (int r = 0; r < 8; ++r) vv[r] = h2b[(size_t)ss[r] * 64 + lane];
#pragma unroll
        for (int r = 0; r < 8; ++r) acc += bf2f(vv[r]);
        j += 8;
    }
    for (; j < c; ++j) {
        int s = elist[base + j];
        acc += bf2f(h2b[(size_t)s * 64 + lane]);
    }
    float di = dis[i];
    float self = bf2f(h2b[(size_t)i * 64 + lane]);
    out[(size_t)i * 64 + lane] = di * (acc + self) + b2[lane];
}

extern "C" void kernel_launch(void* const* d_in, const int* in_sizes, int n_in,
                              void* d_out, int out_size, void* d_ws, size_t ws_size,
                              hipStream_t stream) {
    const float* x     = (const float*)d_in[0];
    const void*  ei    = d_in[1];            // int64 or int32, probed per-block
    const float* W1    = (const float*)d_in[2];
    // d_in[3] = b1: cancels exactly through BatchNorm -> skipped
    const float* gamma = (const float*)d_in[4];
    const float* beta  = (const float*)d_in[5];
    const float* W2    = (const float*)d_in[6];
    const float* b2    = (const float*)d_in[7];
    float* out = (float*)d_out;

    int N = in_sizes[0] / 128;
    int E = in_sizes[1] / 2;
    int NB = (N + BSZ - 1) >> SHIFT;         // 391 buckets for N=100000 (<= NBMAX)

    // ---- workspace layout (~85 MB; all regions 16B-aligned) ----
    size_t Na = ((size_t)N + 3) & ~(size_t)3;
    size_t Ea = ((size_t)E + 3) & ~(size_t)3;
    int*   cnt    = (int*)d_ws;                          // Na
    int*   rowptr = cnt + Na;                            // Na
    int*   gcnt   = rowptr + Na;                         // 1024
    int*   gbase  = gcnt + 1024;                         // 1028 (NB+1 used)
    int*   gcur   = gbase + 1028;                        // 1024
    float* stats  = (float*)(gcur + 1024);               // 512
    float* spart  = stats + 512;                         // 256*256 = 64K floats
    float* dis    = spart + 65536;                       // Na
    int*   elist  = (int*)(dis + Na);                    // Ea
    unsigned int* h1b = (unsigned int*)(elist + Ea);     // Na*64 uints (bf16x2)
    float* agg1   = (float*)(h1b + Na * 64);             // Na*128 f32
    unsigned int* ebuf = (unsigned int*)agg1;            // overlay: dead before k_agg1
    uint4* Whi1   = (uint4*)(agg1 + Na * 128);           // 2048 uint4 = 32 KB
    uint4* Wlo1   = Whi1 + 2048;                         // 32 KB
    uint4* Whi2   = Wlo1 + 2048;                         // 1024 uint4 = 16 KB
    uint4* Wlo2   = Whi2 + 1024;                         // 16 KB
    unsigned int* h2b = h1b;                             // overlay: h1 dead after agg1

    hipMemsetAsync(gcnt, 0, 1024 * sizeof(int), stream);
    hipMemsetAsync(spart, 0, 65536 * sizeof(float), stream);

    int gC    = (E + CHUNK - 1) / CHUNK;     // 391 chunks
    int gG1   = (N + 63) / 64;               // MFMA gemms: 64 rows/block
    int gAgg  = (N + 3) / 4;

    k_prepw<<<12, 256, 0, stream>>>(W1, W2, Whi1, Wlo1, Whi2, Wlo2);
    k_hist<<<gC, 256, 0, stream>>>(ei, gcnt, E, N, NB);
    k_scan<<<1, 1024, 0, stream>>>(gcnt, gbase, gcur, NB);
    k_scatter<<<gC, 256, 0, stream>>>(ei, gcur, ebuf, E, N, NB);
    k_fine<<<NB, 256, 0, stream>>>(ebuf, gbase, cnt, dis, rowptr, elist, N);
    k_gemm1<<<gG1, 256, 0, stream>>>(x, Whi1, Wlo1, dis, (unsigned short*)h1b, N);
    k_agg1<<<gAgg, 256, 0, stream>>>(h1b, dis, rowptr, cnt, elist, agg1, spart, N);
    k_bnfin<<<1, 256, 0, stream>>>(spart, stats, gamma, beta, N);
    k_gemm2<<<gG1, 256, 0, stream>>>(agg1, Whi2, Wlo2, stats, dis, (unsigned short*)h2b, N);
    k_agg2<<<gAgg, 256, 0, stream>>>((const unsigned short*)h2b, dis, rowptr, cnt, elist, b2, out, N);
}

// Round 5
// 384.872 us; speedup vs baseline: 1.7607x; 1.0370x over previous
//
#include <hip/hip_runtime.h>

// GCNEncoder — round 15: fix R14's atomic write amplification in k_agg1.
// R14 counters: fused BN-stats atomics added ~54 MB WRITE_SIZE (+21us) —
// per-block cost is fixed (256 device-scope atomicAdds), so amortize:
// k_agg1 now processes 16 nodes/block (each wave: 4 sequential nodes,
// BN partials accumulated in registers across nodes) -> atomic traffic /4.
// spart shrunk to 64 slices (k_bnfin reads 64KB not 256KB).
// Everything else unchanged from R14.

#define SHIFT 8
#define BSZ   256          // nodes per bucket = 1<<SHIFT
#define CHUNK 4096         // edges per block in hist/scatter
#define EPT   (CHUNK/256)  // edges per thread = 16
#define NBMAX 1024         // supports N <= 262144

typedef short bf16x8 __attribute__((ext_vector_type(8)));
typedef float f32x4  __attribute__((ext_vector_type(4)));

__device__ __forceinline__ unsigned short f2bf(float f) {
    unsigned int u = __float_as_uint(f);
    unsigned int r = (u + 0x7FFFu + ((u >> 16) & 1u)) >> 16;   // RNE
    return (unsigned short)r;
}
__device__ __forceinline__ float bf2f(unsigned short h) {
    return __uint_as_float(((unsigned int)h) << 16);
}
// exact hi/lo split of a float pair, packed as bf16x2 (truncation split:
// x == bf2f(hi) + lo exactly; lo then truncated to bf16, residual ~2^-17|x|)
__device__ __forceinline__ void split2(float a, float b, unsigned int& hi, unsigned int& lo) {
    unsigned int ua = __float_as_uint(a), ub = __float_as_uint(b);
    unsigned int ha = ua & 0xFFFF0000u,  hb = ub & 0xFFFF0000u;
    hi = (ha >> 16) | hb;
    float la = a - __uint_as_float(ha);
    float lb = b - __uint_as_float(hb);
    lo = (__float_as_uint(la) >> 16) | (__float_as_uint(lb) & 0xFFFF0000u);
}
// dtype probe, computed per-block (reads 16 L2-hot ints): 1 => int64 input
__device__ __forceinline__ int detect64(const int* __restrict__ p) {
    int o = 0;
#pragma unroll
    for (int q = 0; q < 16; ++q) o |= p[2 * q + 1];
    return (o == 0) ? 1 : 0;
}

// ---------- pass 1: bucket histogram (LDS-staged) ----------
__global__ __launch_bounds__(256) void k_hist(const void* __restrict__ eiv,
                                              int* __restrict__ gcnt,
                                              int E, int N, int NB) {
    __shared__ int h[NBMAX];
    int t = threadIdx.x;
    for (int u = t; u < NB; u += 256) h[u] = 0;
    __syncthreads();
    int base = blockIdx.x * CHUNK;
    int f = detect64((const int*)eiv);
    const long long* e64 = (const long long*)eiv;
    const int*       e32 = (const int*)eiv;
#pragma unroll
    for (int r = 0; r < EPT; ++r) {
        int e = base + r * 256 + t;
        if (e < E) {
            int s, d;
            if (f) { s = (int)e64[e]; d = (int)e64[E + e]; }
            else   { s = e32[e];      d = e32[E + e]; }
            if ((unsigned)s < (unsigned)N && (unsigned)d < (unsigned)N)
                atomicAdd(&h[d >> SHIFT], 1);
        }
    }
    __syncthreads();
    for (int u = t; u < NB; u += 256) {
        int c = h[u];
        if (c) atomicAdd(&gcnt[u], c);
    }
}

// ---------- pass 2: exclusive prefix over bucket totals ----------
__global__ void k_scan(const int* __restrict__ gcnt, int* __restrict__ gbase,
                       int* __restrict__ gcur, int NB) {
    __shared__ int sh[1024];
    int t = threadIdx.x;
    int v = (t < NB) ? gcnt[t] : 0;
    sh[t] = v;
    __syncthreads();
    for (int off = 1; off < 1024; off <<= 1) {
        int x = sh[t];
        int y = (t >= off) ? sh[t - off] : 0;
        __syncthreads();
        sh[t] = x + y;
        __syncthreads();
    }
    if (t < NB) {
        int ex = sh[t] - v;
        gbase[t] = ex;
        gcur[t]  = ex;
    }
    if (t == 0) gbase[NB] = sh[1023];
}

// ---------- pass 3: scatter edges into bucket regions, clustered ----------
__global__ __launch_bounds__(256) void k_scatter(const void* __restrict__ eiv,
                                                 int* __restrict__ gcur,
                                                 unsigned int* __restrict__ ebuf,
                                                 int E, int N, int NB) {
    __shared__ int lcnt[NBMAX];
    __shared__ int lbase[NBMAX];
    int t = threadIdx.x;
    for (int u = t; u < NB; u += 256) lcnt[u] = 0;
    __syncthreads();
    int base = blockIdx.x * CHUNK;
    int f = detect64((const int*)eiv);
    const long long* e64 = (const long long*)eiv;
    const int*       e32 = (const int*)eiv;
    unsigned int ent[EPT];
    int bk[EPT];
    int off[EPT];
#pragma unroll
    for (int r = 0; r < EPT; ++r) {
        int e = base + r * 256 + t;
        bk[r] = -1;
        if (e < E) {
            int s, d;
            if (f) { s = (int)e64[e]; d = (int)e64[E + e]; }
            else   { s = e32[e];      d = e32[E + e]; }
            if ((unsigned)s < (unsigned)N && (unsigned)d < (unsigned)N) {
                int b = d >> SHIFT;
                bk[r]  = b;
                off[r] = atomicAdd(&lcnt[b], 1);
                ent[r] = ((unsigned int)(d & (BSZ - 1)) << 24) | (unsigned int)s;
            }
        }
    }
    __syncthreads();
    for (int u = t; u < NB; u += 256) {
        int c = lcnt[u];
        lbase[u] = c ? atomicAdd(&gcur[u], c) : 0;
    }
    __syncthreads();
#pragma unroll
    for (int r = 0; r < EPT; ++r)
        if (bk[r] >= 0) ebuf[(size_t)lbase[bk[r]] + off[r]] = ent[r];
}

// ---------- pass 4: per-bucket CSR finalize (counts, dis, rowptr, elist) ----
__global__ __launch_bounds__(256) void k_fine(const unsigned int* __restrict__ ebuf,
                                              const int* __restrict__ gbase,
                                              int* __restrict__ cnt,
                                              float* __restrict__ dis,
                                              int* __restrict__ rowptr,
                                              int* __restrict__ elist, int N) {
    __shared__ int lc[BSZ];
    __shared__ int ls[BSZ];
    int t = threadIdx.x;
    int b = blockIdx.x;
    int start = gbase[b], end = gbase[b + 1];
    int m = end - start;
    lc[t] = 0;
    __syncthreads();
    for (int j = t; j < m; j += 256)
        atomicAdd(&lc[ebuf[start + j] >> 24], 1);
    __syncthreads();
    int v = lc[t];
    ls[t] = v;
    __syncthreads();
    for (int off = 1; off < BSZ; off <<= 1) {
        int x = ls[t];
        int y = (t >= off) ? ls[t - off] : 0;
        __syncthreads();
        ls[t] = x + y;
        __syncthreads();
    }
    int ex = ls[t] - v;
    int i = (b << SHIFT) + t;
    if (i < N) {
        cnt[i]    = v;
        dis[i]    = rsqrtf((float)v + 1.0f);
        rowptr[i] = start + ex;
    }
    lc[t] = ex;        // per-node cursor (bucket-relative)
    __syncthreads();
    for (int j = t; j < m; j += 256) {
        unsigned int e = ebuf[start + j];
        int p = atomicAdd(&lc[e >> 24], 1);
        elist[start + p] = (int)(e & 0xFFFFFFu);
    }
}

// ---------- W1+W2 -> fragment-ordered bf16 hi/lo buffers (one launch) ------
// slot = (nt*4 + kt)*64 + lane ; lane holds B[k][n] for n = nt*16+(lane&15),
// k = kt*32 + 8*(lane>>4) + j, j=0..7 packed low-to-high (same k-map as A).
__global__ __launch_bounds__(256) void k_prepw(const float* __restrict__ W1,
                                               const float* __restrict__ W2,
                                               uint4* __restrict__ Whi1,
                                               uint4* __restrict__ Wlo1,
                                               uint4* __restrict__ Whi2,
                                               uint4* __restrict__ Wlo2) {
    int idx = blockIdx.x * 256 + threadIdx.x;
    const float* W; uint4 *H, *L; int slot;
    if (idx < 2048)      { W = W1; H = Whi1; L = Wlo1; slot = idx; }
    else if (idx < 3072) { W = W2; H = Whi2; L = Wlo2; slot = idx - 2048; }
    else return;
    int lane = slot & 63, kt = (slot >> 6) & 3, nt = slot >> 8;
    int o = nt * 16 + (lane & 15);
    int k0 = kt * 32 + (lane >> 4) * 8;
    const float* p = W + (size_t)o * 128 + k0;
    unsigned int h[4], l[4];
#pragma unroll
    for (int pr = 0; pr < 4; ++pr) split2(p[2 * pr], p[2 * pr + 1], h[pr], l[pr]);
    H[slot] = make_uint4(h[0], h[1], h[2], h[3]);
    L[slot] = make_uint4(l[0], l[1], l[2], l[3]);
}

// ---------- GEMM1 (MFMA): h1s[n][o] (bf16) = dis[n] * (x[n]·W1[o]) ----------
__global__ __launch_bounds__(256) void k_gemm1(const float* __restrict__ x,
                                               const uint4* __restrict__ Whi,
                                               const uint4* __restrict__ Wlo,
                                               const float* __restrict__ dis,
                                               unsigned short* __restrict__ h1b, int N) {
    __shared__ uint4 Ahi[1024];   // [ (c*4+kt)*64 + lane ]
    __shared__ uint4 Alo[1024];
    int t = threadIdx.x;
    int n0 = blockIdx.x * 64;
    // ---- phase 1: x -> hi/lo fragments in LDS ----
    for (int s = t; s < 1024; s += 256) {
        int lane = s & 63, kt = (s >> 6) & 3, c = s >> 8;
        int row = n0 + c * 16 + (lane & 15);
        int rr = min(row, N - 1);
        int k0 = kt * 32 + (lane >> 4) * 8;
        const float4* p = (const float4*)(x + (size_t)rr * 128 + k0);
        float4 u0 = p[0], u1 = p[1];
        unsigned int h0, h1, h2, h3, l0, l1, l2, l3;
        split2(u0.x, u0.y, h0, l0);
        split2(u0.z, u0.w, h1, l1);
        split2(u1.x, u1.y, h2, l2);
        split2(u1.z, u1.w, h3, l3);
        Ahi[s] = make_uint4(h0, h1, h2, h3);
        Alo[s] = make_uint4(l0, l1, l2, l3);
    }
    __syncthreads();
    // ---- phase 2: MFMA ----
    int w = t >> 6, lane = t & 63;
    bf16x8 ah[4], al[4];
#pragma unroll
    for (int kt = 0; kt < 4; ++kt) {
        ah[kt] = ((const bf16x8*)Ahi)[(w * 4 + kt) * 64 + lane];
        al[kt] = ((const bf16x8*)Alo)[(w * 4 + kt) * 64 + lane];
    }
    f32x4 acc[8];
#pragma unroll
    for (int nt = 0; nt < 8; ++nt) {
        acc[nt] = (f32x4)(0.f);
#pragma unroll
        for (int kt = 0; kt < 4; ++kt) {
            bf16x8 bh = ((const bf16x8*)Whi)[(nt * 4 + kt) * 64 + lane];
            bf16x8 bl = ((const bf16x8*)Wlo)[(nt * 4 + kt) * 64 + lane];
            acc[nt] = __builtin_amdgcn_mfma_f32_16x16x32_bf16(ah[kt], bh, acc[nt], 0, 0, 0);
            acc[nt] = __builtin_amdgcn_mfma_f32_16x16x32_bf16(ah[kt], bl, acc[nt], 0, 0, 0);
            acc[nt] = __builtin_amdgcn_mfma_f32_16x16x32_bf16(al[kt], bh, acc[nt], 0, 0, 0);
        }
    }
    // ---- epilogue: scale by dis, pack bf16, store ----
    int r0 = n0 + w * 16 + (lane >> 4) * 4;
    float dv[4];
#pragma unroll
    for (int r = 0; r < 4; ++r) {
        int row = r0 + r;
        dv[r] = (row < N) ? dis[row] : 0.f;
    }
#pragma unroll
    for (int nt = 0; nt < 8; ++nt) {
        int col = nt * 16 + (lane & 15);
#pragma unroll
        for (int r = 0; r < 4; ++r) {
            int row = r0 + r;
            if (row < N) h1b[(size_t)row * 128 + col] = f2bf(dv[r] * acc[nt][r]);
        }
    }
}

// ---------- layer-1 gather + fused BN-stats, 16 nodes/block ----------
// agg1[i] = dis_i * ( sum_edges h1s[s] + h1s[i] ); each wave processes 4
// sequential nodes, BN partials held in registers across nodes; one LDS
// reduce + 256 atomics per block (4x fewer blocks than R14 -> /4 traffic).
__global__ __launch_bounds__(256) void k_agg1(const unsigned int* __restrict__ h1b,
                                              const float* __restrict__ dis,
                                              const int* __restrict__ rowptr,
                                              const int* __restrict__ cnt,
                                              const int* __restrict__ elist,
                                              float* __restrict__ agg1,
                                              float* __restrict__ spart, int N) {
    int t = threadIdx.x;
    int lane = t & 63;
    int i0 = blockIdx.x * 16 + (t >> 6) * 4;
    float sx = 0.f, sy = 0.f, qx = 0.f, qy = 0.f;
#pragma unroll
    for (int k = 0; k < 4; ++k) {
        int i = i0 + k;
        bool act = (i < N);
        float accx = 0.f, accy = 0.f;
        int base = 0, c = 0;
        if (act) { base = rowptr[i]; c = cnt[i]; }
        int j = 0;
        for (; j + 16 <= c; j += 16) {
            int ss[16];
#pragma unroll
            for (int r = 0; r < 16; ++r) ss[r] = elist[base + j + r];
            unsigned int vv[16];
#pragma unroll
            for (int r = 0; r < 16; ++r) vv[r] = h1b[(size_t)ss[r] * 64 + lane];  // 256B/row
#pragma unroll
            for (int r = 0; r < 16; ++r) {
                accx += bf2f((unsigned short)(vv[r] & 0xFFFF));
                accy += bf2f((unsigned short)(vv[r] >> 16));
            }
        }
        if (j + 8 <= c) {
            int ss[8];
#pragma unroll
            for (int r = 0; r < 8; ++r) ss[r] = elist[base + j + r];
            unsigned int vv[8];
#pragma unroll
            for (int r = 0; r < 8; ++r) vv[r] = h1b[(size_t)ss[r] * 64 + lane];
#pragma unroll
            for (int r = 0; r < 8; ++r) {
                accx += bf2f((unsigned short)(vv[r] & 0xFFFF));
                accy += bf2f((unsigned short)(vv[r] >> 16));
            }
            j += 8;
        }
        for (; j < c; ++j) {
            int s = elist[base + j];
            unsigned int v = h1b[(size_t)s * 64 + lane];
            accx += bf2f((unsigned short)(v & 0xFFFF));
            accy += bf2f((unsigned short)(v >> 16));
        }
        if (act) {
            float di = dis[i];
            unsigned int sv = h1b[(size_t)i * 64 + lane];
            float rx = di * (accx + bf2f((unsigned short)(sv & 0xFFFF)));
            float ry = di * (accy + bf2f((unsigned short)(sv >> 16)));
            ((float2*)agg1)[(size_t)i * 64 + lane] = make_float2(rx, ry);
            sx += rx; sy += ry; qx += rx * rx; qy += ry * ry;
        }
    }
    // ---- fused BN partial stats: features 2*lane, 2*lane+1 ----
    __shared__ float4 red[256];
    red[t] = make_float4(sx, sy, qx, qy);
    __syncthreads();
    if (t < 64) {
        float4 a = red[t], b = red[t + 64], cc = red[t + 128], d = red[t + 192];
        float ssx = a.x + b.x + cc.x + d.x;
        float ssy = a.y + b.y + cc.y + d.y;
        float sqx = a.z + b.z + cc.z + d.z;
        float sqy = a.w + b.w + cc.w + d.w;
        float* sp = spart + ((size_t)(blockIdx.x & 63) << 8);
        atomicAdd(&sp[2 * t],           ssx);
        atomicAdd(&sp[2 * t + 1],       ssy);
        atomicAdd(&sp[128 + 2 * t],     sqx);
        atomicAdd(&sp[128 + 2 * t + 1], sqy);
    }
}

// ---------- BN finalize: reduce spart slices, then scale/shift ----------
__global__ void k_bnfin(const float* __restrict__ spart, float* __restrict__ stats,
                        const float* __restrict__ gamma,
                        const float* __restrict__ beta, int N) {
    __shared__ float sred[256];
    int t = threadIdx.x;   // 256 threads
    float s = 0.f;
    for (int sl = 0; sl < 64; ++sl) s += spart[sl * 256 + t];
    sred[t] = s;
    __syncthreads();
    if (t < 128) {
        float invN = 1.0f / (float)N;
        float mean = sred[t] * invN;
        float var = sred[128 + t] * invN - mean * mean;
        var = fmaxf(var, 0.f);
        float inv = rsqrtf(var + 1e-5f);
        float sc = gamma[t] * inv;
        stats[256 + t] = sc;
        stats[384 + t] = beta[t] - mean * sc;
    }
}

// ---------- GEMM2 (MFMA): h2s[n][o] (bf16) = dis[n]*(relu(bn(agg1[n]))·W2[o])
// Same structure as k_gemm1; BN+ReLU applied during LDS fragment staging.
__global__ __launch_bounds__(256) void k_gemm2(const float* __restrict__ agg1,
                                               const uint4* __restrict__ Whi,
                                               const uint4* __restrict__ Wlo,
                                               const float* __restrict__ stats,
                                               const float* __restrict__ dis,
                                               unsigned short* __restrict__ h2b, int N) {
    __shared__ uint4 Ahi[1024];   // [ (c*4+kt)*64 + lane ]
    __shared__ uint4 Alo[1024];
    int t = threadIdx.x;
    int n0 = blockIdx.x * 64;
    const float4* st = (const float4*)stats;
    // ---- phase 1: relu(bn(agg1)) -> hi/lo fragments in LDS ----
    for (int s = t; s < 1024; s += 256) {
        int lane = s & 63, kt = (s >> 6) & 3, c = s >> 8;
        int row = n0 + c * 16 + (lane & 15);
        int rr = min(row, N - 1);
        int k0 = kt * 32 + (lane >> 4) * 8;
        const float4* p = (const float4*)(agg1 + (size_t)rr * 128 + k0);
        float4 a0 = p[0], a1 = p[1];
        float4 c0 = st[64 + (k0 >> 2)], c1 = st[65 + (k0 >> 2)];
        float4 s0 = st[96 + (k0 >> 2)], s1 = st[97 + (k0 >> 2)];
        float v0 = fmaxf(a0.x * c0.x + s0.x, 0.f);
        float v1 = fmaxf(a0.y * c0.y + s0.y, 0.f);
        float v2 = fmaxf(a0.z * c0.z + s0.z, 0.f);
        float v3 = fmaxf(a0.w * c0.w + s0.w, 0.f);
        float v4 = fmaxf(a1.x * c1.x + s1.x, 0.f);
        float v5 = fmaxf(a1.y * c1.y + s1.y, 0.f);
        float v6 = fmaxf(a1.z * c1.z + s1.z, 0.f);
        float v7 = fmaxf(a1.w * c1.w + s1.w, 0.f);
        unsigned int h0, h1, h2, h3, l0, l1, l2, l3;
        split2(v0, v1, h0, l0);
        split2(v2, v3, h1, l1);
        split2(v4, v5, h2, l2);
        split2(v6, v7, h3, l3);
        Ahi[s] = make_uint4(h0, h1, h2, h3);
        Alo[s] = make_uint4(l0, l1, l2, l3);
    }
    __syncthreads();
    // ---- phase 2: MFMA (4 nt x 4 kt x 3) ----
    int w = t >> 6, lane = t & 63;
    bf16x8 ah[4], al[4];
#pragma unroll
    for (int kt = 0; kt < 4; ++kt) {
        ah[kt] = ((const bf16x8*)Ahi)[(w * 4 + kt) * 64 + lane];
        al[kt] = ((const bf16x8*)Alo)[(w * 4 + kt) * 64 + lane];
    }
    f32x4 acc[4];
#pragma unroll
    for (int nt = 0; nt < 4; ++nt) {
        acc[nt] = (f32x4)(0.f);
#pragma unroll
        for (int kt = 0; kt < 4; ++kt) {
            bf16x8 bh = ((const bf16x8*)Whi)[(nt * 4 + kt) * 64 + lane];
            bf16x8 bl = ((const bf16x8*)Wlo)[(nt * 4 + kt) * 64 + lane];
            acc[nt] = __builtin_amdgcn_mfma_f32_16x16x32_bf16(ah[kt], bh, acc[nt], 0, 0, 0);
            acc[nt] = __builtin_amdgcn_mfma_f32_16x16x32_bf16(ah[kt], bl, acc[nt], 0, 0, 0);
            acc[nt] = __builtin_amdgcn_mfma_f32_16x16x32_bf16(al[kt], bh, acc[nt], 0, 0, 0);
        }
    }
    // ---- epilogue: scale by dis, pack bf16, store (64 cols) ----
    int r0 = n0 + w * 16 + (lane >> 4) * 4;
    float dv[4];
#pragma unroll
    for (int r = 0; r < 4; ++r) {
        int row = r0 + r;
        dv[r] = (row < N) ? dis[row] : 0.f;
    }
#pragma unroll
    for (int nt = 0; nt < 4; ++nt) {
        int col = nt * 16 + (lane & 15);
#pragma unroll
        for (int r = 0; r < 4; ++r) {
            int row = r0 + r;
            if (row < N) h2b[(size_t)row * 64 + col] = f2bf(dv[r] * acc[nt][r]);
        }
    }
}

// ---------- layer-2 gather: pre-scaled bf16 rows, 16-way prefetch ----------
// out[i] = dis_i * ( sum_edges h2s[s] + h2s[i] ) + b2
__global__ __launch_bounds__(256) void k_agg2(const unsigned short* __restrict__ h2b,
                                              const float* __restrict__ dis,
                                              const int* __restrict__ rowptr,
                                              const int* __restrict__ cnt,
                                              const int* __restrict__ elist,
                                              const float* __restrict__ b2,
                                              float* __restrict__ out, int N) {
    int lane = threadIdx.x & 63;
    int i = blockIdx.x * 4 + (threadIdx.x >> 6);
    if (i >= N) return;
    float acc = 0.f;
    int base = rowptr[i], c = cnt[i];
    int j = 0;
    for (; j + 16 <= c; j += 16) {
        int ss[16];
#pragma unroll
        for (int r = 0; r < 16; ++r) ss[r] = elist[base + j + r];
        unsigned short vv[16];
#pragma unroll
        for (int r = 0; r < 16; ++r) vv[r] = h2b[(size_t)ss[r] * 64 + lane];  // 128B/row
#pragma unroll
        for (int r = 0; r < 16; ++r) acc += bf2f(vv[r]);
    }
    if (j + 8 <= c) {
        int ss[8];
#pragma unroll
        for (int r = 0; r < 8; ++r) ss[r] = elist[base + j + r];
        unsigned short vv[8];
#pragma unroll
        for (int r = 0; r < 8; ++r) vv[r] = h2b[(size_t)ss[r] * 64 + lane];
#pragma unroll
        for (int r = 0; r < 8; ++r) acc += bf2f(vv[r]);
        j += 8;
    }
    for (; j < c; ++j) {
        int s = elist[base + j];
        acc += bf2f(h2b[(size_t)s * 64 + lane]);
    }
    float di = dis[i];
    float self = bf2f(h2b[(size_t)i * 64 + lane]);
    out[(size_t)i * 64 + lane] = di * (acc + self) + b2[lane];
}

extern "C" void kernel_launch(void* const* d_in, const int* in_sizes, int n_in,
                              void* d_out, int out_size, void* d_ws, size_t ws_size,
                              hipStream_t stream) {
    const float* x     = (const float*)d_in[0];
    const void*  ei    = d_in[1];            // int64 or int32, probed per-block
    const float* W1    = (const float*)d_in[2];
    // d_in[3] = b1: cancels exactly through BatchNorm -> skipped
    const float* gamma = (const float*)d_in[4];
    const float* beta  = (const float*)d_in[5];
    const float* W2    = (const float*)d_in[6];
    const float* b2    = (const float*)d_in[7];
    float* out = (float*)d_out;

    int N = in_sizes[0] / 128;
    int E = in_sizes[1] / 2;
    int NB = (N + BSZ - 1) >> SHIFT;         // 391 buckets for N=100000 (<= NBMAX)

    // ---- workspace layout (~85 MB; all regions 16B-aligned) ----
    size_t Na = ((size_t)N + 3) & ~(size_t)3;
    size_t Ea = ((size_t)E + 3) & ~(size_t)3;
    int*   cnt    = (int*)d_ws;                          // Na
    int*   rowptr = cnt + Na;                            // Na
    int*   gcnt   = rowptr + Na;                         // 1024
    int*   gbase  = gcnt + 1024;                         // 1028 (NB+1 used)
    int*   gcur   = gbase + 1028;                        // 1024
    float* stats  = (float*)(gcur + 1024);               // 512
    float* spart  = stats + 512;                         // 64*256 = 16K floats
    float* dis    = spart + 65536;                       // Na (keep R14 offsets)
    int*   elist  = (int*)(dis + Na);                    // Ea
    unsigned int* h1b = (unsigned int*)(elist + Ea);     // Na*64 uints (bf16x2)
    float* agg1   = (float*)(h1b + Na * 64);             // Na*128 f32
    unsigned int* ebuf = (unsigned int*)agg1;            // overlay: dead before k_agg1
    uint4* Whi1   = (uint4*)(agg1 + Na * 128);           // 2048 uint4 = 32 KB
    uint4* Wlo1   = Whi1 + 2048;                         // 32 KB
    uint4* Whi2   = Wlo1 + 2048;                         // 1024 uint4 = 16 KB
    uint4* Wlo2   = Whi2 + 1024;                         // 16 KB
    unsigned int* h2b = h1b;                             // overlay: h1 dead after agg1

    hipMemsetAsync(gcnt, 0, 1024 * sizeof(int), stream);
    hipMemsetAsync(spart, 0, 16384 * sizeof(float), stream);

    int gC    = (E + CHUNK - 1) / CHUNK;     // 391 chunks
    int gG1   = (N + 63) / 64;               // MFMA gemms: 64 rows/block
    int gAgg1 = (N + 15) / 16;               // 16 nodes/block
    int gAgg2 = (N + 3) / 4;

    k_prepw<<<12, 256, 0, stream>>>(W1, W2, Whi1, Wlo1, Whi2, Wlo2);
    k_hist<<<gC, 256, 0, stream>>>(ei, gcnt, E, N, NB);
    k_scan<<<1, 1024, 0, stream>>>(gcnt, gbase, gcur, NB);
    k_scatter<<<gC, 256, 0, stream>>>(ei, gcur, ebuf, E, N, NB);
    k_fine<<<NB, 256, 0, stream>>>(ebuf, gbase, cnt, dis, rowptr, elist, N);
    k_gemm1<<<gG1, 256, 0, stream>>>(x, Whi1, Wlo1, dis, (unsigned short*)h1b, N);
    k_agg1<<<gAgg1, 256, 0, stream>>>(h1b, dis, rowptr, cnt, elist, agg1, spart, N);
    k_bnfin<<<1, 256, 0, stream>>>(spart, stats, gamma, beta, N);
    k_gemm2<<<gG1, 256, 0, stream>>>(agg1, Whi2, Wlo2, stats, dis, (unsigned short*)h2b, N);
    k_agg2<<<gAgg2, 256, 0, stream>>>((const unsigned short*)h2b, dis, rowptr, cnt, elist, b2, out, N);
}